// Round 4
// baseline (1044.547 us; speedup 1.0000x reference)
//
#include <hip/hip_runtime.h>

// S,P,M=(128,2048,64), NC,NB=(16,8), H,W=512, EXTENT=12, EPS=1e-9
#define NS   128
#define NP   2048
#define NM   64
#define NCYL 16
#define NBOX 8
#define IH   512
#define IW   512
#define FEXT 12.0f
#define FEPS 1e-9f
#define PXSCALE ((float)IW / (2.0f * FEXT))
#define SPT  4   // sources per thread (ILP + reuse)

__device__ __forceinline__ float frcp(float x)   { return __builtin_amdgcn_rcpf(x); }
__device__ __forceinline__ float frsq(float x)   { return __builtin_amdgcn_rsqf(x); }
__device__ __forceinline__ float fsqrt_(float x) { return __builtin_amdgcn_sqrtf(x); }

__global__ __launch_bounds__(256) void render_kernel(
    const float* __restrict__ sources, const float* __restrict__ mpts,
    const float* __restrict__ mnrm,    const float* __restrict__ mpos,
    const float* __restrict__ mrot,
    const float* __restrict__ cp1g, const float* __restrict__ cp2g,
    const float* __restrict__ crad, const float* __restrict__ bp1g,
    const float* __restrict__ bp2g, const float* __restrict__ spp,
    const float* __restrict__ spn,  float* __restrict__ img)
{
    // cyl[c][0]=(p1x,p1y,p1z,L); cyl[c][1]=(ax,ay,az,r^2); box[b]=(lo),(hi)
    __shared__ float4 s_cyl[NCYL][2];
    __shared__ float4 s_box[NBOX][2];

    const int t  = threadIdx.x;
    const int n  = blockIdx.x * 256 + t;   // point index
    const int s0 = blockIdx.y * SPT;       // first source index
    const int m  = blockIdx.z;             // mirror index

    // Issue per-thread point loads early (latency overlaps LDS fill + barrier).
    const long idx = ((long)m * NP + n) * 3;
    float px = mpts[idx+0], py = mpts[idx+1], pz = mpts[idx+2];
    float nx = mnrm[idx+0], ny = mnrm[idx+1], nz = mnrm[idx+2];

    if (t < NCYL) {
        float p1x = cp1g[t*3+0], p1y = cp1g[t*3+1], p1z = cp1g[t*3+2];
        float axx = cp2g[t*3+0] - p1x;
        float axy = cp2g[t*3+1] - p1y;
        float axz = cp2g[t*3+2] - p1z;
        float L   = sqrtf(axx*axx + axy*axy + axz*axz);
        float inv = 1.0f / (L + FEPS);
        float r   = crad[t];
        s_cyl[t][0] = make_float4(p1x, p1y, p1z, L);
        s_cyl[t][1] = make_float4(axx*inv, axy*inv, axz*inv, r*r);
    } else if (t < NCYL + NBOX) {
        int b = t - NCYL;
        s_box[b][0] = make_float4(bp1g[b*3+0], bp1g[b*3+1], bp1g[b*3+2], 0.0f);
        s_box[b][1] = make_float4(bp2g[b*3+0], bp2g[b*3+1], bp2g[b*3+2], 0.0f);
    }
    __syncthreads();

    // Block-uniform scalars.
    float R0 = mrot[m*9+0], R1 = mrot[m*9+1], R2 = mrot[m*9+2];
    float R3 = mrot[m*9+3], R4 = mrot[m*9+4], R5 = mrot[m*9+5];
    float R6 = mrot[m*9+6], R7 = mrot[m*9+7], R8 = mrot[m*9+8];
    float posx = mpos[m*3+0], posy = mpos[m*3+1], posz = mpos[m*3+2];
    float sppx = spp[0], sppy = spp[1], sppz = spp[2];
    float spnx = spn[0], spny = spn[1], spnz = spn[2];

    // tp = R@p + pos ; tn = R@n
    float tpx = R0*px + R1*py + R2*pz + posx;
    float tpy = R3*px + R4*py + R5*pz + posy;
    float tpz = R6*px + R7*py + R8*pz + posz;
    float tnx = R0*nx + R1*ny + R2*nz;
    float tny = R3*nx + R4*ny + R5*nz;
    float tnz = R6*nx + R7*ny + R8*nz;

    // Shadow-ray directions u_j = (src_j - tp)/|src_j - tp|  (= -d_j)
    float ux[SPT], uy[SPT], uz[SPT];
    bool  hit[SPT];
    #pragma unroll
    for (int j = 0; j < SPT; j++) {
        float sx = sources[(s0+j)*3+0], sy = sources[(s0+j)*3+1], sz = sources[(s0+j)*3+2];
        float ex = tpx - sx, ey = tpy - sy, ez = tpz - sz;   // d before normalize
        float il = frsq(ex*ex + ey*ey + ez*ez);
        ux[j] = -ex*il; uy[j] = -ey*il; uz[j] = -ez*il;
        hit[j] = false;
    }

    // Cylinders — branchless, source-invariant parts hoisted.
    // A = 1 - ua^2 ; B/2 = oc.u - oa*ua ; C = |oc|^2 - oa^2 - r^2
    #pragma unroll
    for (int c = 0; c < NCYL; c++) {
        float4 c0 = s_cyl[c][0];   // p1, L
        float4 c1 = s_cyl[c][1];   // a, r^2
        float ocx = tpx - c0.x, ocy = tpy - c0.y, ocz = tpz - c0.z;
        float oa  = ocx*c1.x + ocy*c1.y + ocz*c1.z;
        float Cc  = ocx*ocx + ocy*ocy + ocz*ocz - oa*oa - c1.w;
        float L   = c0.w;
        #pragma unroll
        for (int j = 0; j < SPT; j++) {
            float ua   = ux[j]*c1.x + uy[j]*c1.y + uz[j]*c1.z;
            float A    = fmaf(-ua, ua, 1.0f);
            float Bh   = fmaf(ux[j], ocx, fmaf(uy[j], ocy, uz[j]*ocz)) - oa*ua;
            float disc = fmaf(Bh, Bh, -A*Cc);
            float sq   = fsqrt_(fmaxf(disc, 0.0f));
            float ia   = frcp(A + 0.5f*FEPS);
            float t1   = (-Bh - sq) * ia;
            float t2   = (-Bh + sq) * ia;
            float ax1  = fmaf(t1, ua, oa);
            float ax2  = fmaf(t2, ua, oa);
            bool dpos  = disc > 0.0f;
            hit[j] = hit[j] | (dpos & (t1 > FEPS) & (ax1 >= 0.0f) & (ax1 <= L))
                            | (dpos & (t2 > FEPS) & (ax2 >= 0.0f) & (ax2 <= L));
        }
    }

    // Boxes — branchless slab test, corner deltas shared across sources.
    float ivx[SPT], ivy[SPT], ivz[SPT];
    #pragma unroll
    for (int j = 0; j < SPT; j++) {
        ivx[j] = frcp((fabsf(ux[j]) < FEPS) ? FEPS : ux[j]);
        ivy[j] = frcp((fabsf(uy[j]) < FEPS) ? FEPS : uy[j]);
        ivz[j] = frcp((fabsf(uz[j]) < FEPS) ? FEPS : uz[j]);
    }
    #pragma unroll
    for (int b = 0; b < NBOX; b++) {
        float4 b1 = s_box[b][0];
        float4 b2 = s_box[b][1];
        float r1x = b1.x - tpx, r1y = b1.y - tpy, r1z = b1.z - tpz;
        float r2x = b2.x - tpx, r2y = b2.y - tpy, r2z = b2.z - tpz;
        #pragma unroll
        for (int j = 0; j < SPT; j++) {
            float t0x = r1x*ivx[j], t1x = r2x*ivx[j];
            float t0y = r1y*ivy[j], t1y = r2y*ivy[j];
            float t0z = r1z*ivz[j], t1z = r2z*ivz[j];
            float tmin = fmaxf(fmaxf(fminf(t0x,t1x), fminf(t0y,t1y)), fminf(t0z,t1z));
            float tmax = fminf(fminf(fmaxf(t0x,t1x), fmaxf(t0y,t1y)), fmaxf(t0z,t1z));
            hit[j] = hit[j] | (tmax >= fmaxf(tmin, FEPS));
        }
    }

    // Epilogue: reflect, project to sensor plane, scatter.
    float num = (sppx-tpx)*spnx + (sppy-tpy)*spny + (sppz-tpz)*spnz;  // shared
    #pragma unroll
    for (int j = 0; j < SPT; j++) {
        float dx = -ux[j], dy = -uy[j], dz = -uz[j];
        float dn = dx*tnx + dy*tny + dz*tnz;
        float rx = fmaf(-2.0f*dn, tnx, dx);
        float ry = fmaf(-2.0f*dn, tny, dy);
        float rz = fmaf(-2.0f*dn, tnz, dz);
        float cosv  = fabsf(dn);
        float denom = rx*spnx + ry*spny + rz*spnz;
        float tt = num * frcp(denom + FEPS);
        float qx = fmaf(tt, rx, tpx);
        float qy = fmaf(tt, ry, tpy);
        float fx = (qx + FEXT) * PXSCALE;
        float fy = (qy + FEXT) * PXSCALE;
        float fxf = floorf(fx), fyf = floorf(fy);
        bool inb = (fxf >= 0.0f) & (fxf < (float)IW) & (fyf >= 0.0f) & (fyf < (float)IH)
                   & (!hit[j]);
        if (inb) {
            atomicAdd(&img[(int)fyf * IW + (int)fxf], cosv);
        }
    }
}

extern "C" void kernel_launch(void* const* d_in, const int* in_sizes, int n_in,
                              void* d_out, int out_size, void* d_ws, size_t ws_size,
                              hipStream_t stream) {
    const float* sources = (const float*)d_in[0];
    const float* mpts    = (const float*)d_in[1];
    const float* mnrm    = (const float*)d_in[2];
    const float* mpos    = (const float*)d_in[3];
    const float* mrot    = (const float*)d_in[4];
    const float* cp1     = (const float*)d_in[5];
    const float* cp2     = (const float*)d_in[6];
    const float* crad    = (const float*)d_in[7];
    const float* bp1     = (const float*)d_in[8];
    const float* bp2     = (const float*)d_in[9];
    const float* spp     = (const float*)d_in[10];
    const float* spn     = (const float*)d_in[11];

    float* img = (float*)d_out;  // fp32 accumulator IS the output
    hipMemsetAsync(img, 0, (size_t)IH * IW * sizeof(float), stream);

    dim3 grid(NP / 256, NS / SPT, NM);  // (8, 32, 64) = 16384 blocks
    render_kernel<<<grid, 256, 0, stream>>>(sources, mpts, mnrm, mpos, mrot,
                                            cp1, cp2, crad, bp1, bp2, spp, spn, img);
}

// Round 5
// 956.983 us; speedup vs baseline: 1.0915x; 1.0915x over previous
//
#include <hip/hip_runtime.h>

// S,P,M=(128,2048,64), NC,NB=(16,8), H,W=512, EXTENT=12, EPS=1e-9
#define NS   128
#define NP   2048
#define NM   64
#define NCYL 16
#define NBOX 8
#define IH   512
#define IW   512
#define FEXT 12.0f
#define FEPS 1e-9f
#define PXSCALE ((float)IW / (2.0f * FEXT))

__device__ __forceinline__ float frcp(float x)   { return __builtin_amdgcn_rcpf(x); }
__device__ __forceinline__ float frsq(float x)   { return __builtin_amdgcn_rsqf(x); }
__device__ __forceinline__ float fsqrt_(float x) { return __builtin_amdgcn_sqrtf(x); }

// min 4 waves/EU -> VGPR cap 128; enough room for the scheduler to pipeline
// the unrolled occluder loops, without R4's occupancy collapse.
__global__ __launch_bounds__(256, 4) void render_kernel(
    const float* __restrict__ sources, const float* __restrict__ mpts,
    const float* __restrict__ mnrm,    const float* __restrict__ mpos,
    const float* __restrict__ mrot,
    const float* __restrict__ cp1g, const float* __restrict__ cp2g,
    const float* __restrict__ crad, const float* __restrict__ bp1g,
    const float* __restrict__ bp2g, const float* __restrict__ spp,
    const float* __restrict__ spn,  float* __restrict__ img)
{
    // cyl[c][0]=(p1x,p1y,p1z,L); cyl[c][1]=(ax,ay,az,r^2); box[b]=(lo),(hi)
    __shared__ float4 s_cyl[NCYL][2];
    __shared__ float4 s_box[NBOX][2];

    const int t = threadIdx.x;
    const int n = blockIdx.x * 256 + t;   // point index
    const int s = blockIdx.y;             // source index
    const int m = blockIdx.z;             // mirror index

    // Per-thread point loads issued early (overlap LDS fill + barrier).
    const long idx = ((long)m * NP + n) * 3;
    float px = mpts[idx+0], py = mpts[idx+1], pz = mpts[idx+2];
    float nx = mnrm[idx+0], ny = mnrm[idx+1], nz = mnrm[idx+2];

    if (t < NCYL) {
        float p1x = cp1g[t*3+0], p1y = cp1g[t*3+1], p1z = cp1g[t*3+2];
        float axx = cp2g[t*3+0] - p1x;
        float axy = cp2g[t*3+1] - p1y;
        float axz = cp2g[t*3+2] - p1z;
        float L   = sqrtf(axx*axx + axy*axy + axz*axz);
        float inv = 1.0f / (L + FEPS);
        float r   = crad[t];
        s_cyl[t][0] = make_float4(p1x, p1y, p1z, L);
        s_cyl[t][1] = make_float4(axx*inv, axy*inv, axz*inv, r*r);
    } else if (t < NCYL + NBOX) {
        int b = t - NCYL;
        s_box[b][0] = make_float4(bp1g[b*3+0], bp1g[b*3+1], bp1g[b*3+2], 0.0f);
        s_box[b][1] = make_float4(bp2g[b*3+0], bp2g[b*3+1], bp2g[b*3+2], 0.0f);
    }
    __syncthreads();

    // Block-uniform scalars.
    float R0 = mrot[m*9+0], R1 = mrot[m*9+1], R2 = mrot[m*9+2];
    float R3 = mrot[m*9+3], R4 = mrot[m*9+4], R5 = mrot[m*9+5];
    float R6 = mrot[m*9+6], R7 = mrot[m*9+7], R8 = mrot[m*9+8];
    float posx = mpos[m*3+0], posy = mpos[m*3+1], posz = mpos[m*3+2];
    float sx = sources[s*3+0], sy = sources[s*3+1], sz = sources[s*3+2];
    float sppx = spp[0], sppy = spp[1], sppz = spp[2];
    float spnx = spn[0], spny = spn[1], spnz = spn[2];

    // tp = R@p + pos ; tn = R@n
    float tpx = R0*px + R1*py + R2*pz + posx;
    float tpy = R3*px + R4*py + R5*pz + posy;
    float tpz = R6*px + R7*py + R8*pz + posz;
    float tnx = R0*nx + R1*ny + R2*nz;
    float tny = R3*nx + R4*ny + R5*nz;
    float tnz = R6*nx + R7*ny + R8*nz;

    // d = normalize(tp - src);  u = -d (shadow ray toward source), |u| = 1
    float dx = tpx - sx, dy = tpy - sy, dz = tpz - sz;
    float il = frsq(dx*dx + dy*dy + dz*dz);
    dx *= il; dy *= il; dz *= il;
    float ux = -dx, uy = -dy, uz = -dz;

    bool hit = false;

    // Cylinders — branchless, division-free.
    // With |u|=1:  A = 1-ua^2,  B/2 = oc.u - oa*ua,  C = |oc|^2 - oa^2 - r^2.
    // t_i = q_i / Ah with Ah = A + eps/2 > 0 and q_i = -Bh -/+ sqrt(Bh^2 - A*C);
    // all range checks are multiplied through by Ah (exact, sign-preserving).
    #pragma unroll
    for (int c = 0; c < NCYL; c++) {
        float4 c0 = s_cyl[c][0];   // p1, L
        float4 c1 = s_cyl[c][1];   // a, r^2
        float ocx = tpx - c0.x, ocy = tpy - c0.y, ocz = tpz - c0.z;
        float oa  = ocx*c1.x + ocy*c1.y + ocz*c1.z;
        float Cc  = ocx*ocx + ocy*ocy + ocz*ocz - oa*oa - c1.w;
        float ua  = ux*c1.x + uy*c1.y + uz*c1.z;
        float ocu = ux*ocx + uy*ocy + uz*ocz;
        float Bh  = fmaf(-oa, ua, ocu);
        float A   = fmaf(-ua, ua, 1.0f);
        float disc = fmaf(Bh, Bh, -(A*Cc));          // = disc_ref / 4
        float sq   = fsqrt_(fmaxf(disc, 0.0f));
        float Ah   = A + 0.5f*FEPS;
        float q1   = -Bh - sq;
        float q2   = -Bh + sq;
        float oaA  = oa * Ah;
        float LA   = c0.w * Ah;
        float epsA = FEPS * Ah;
        float ax1A = fmaf(q1, ua, oaA);
        float ax2A = fmaf(q2, ua, oaA);
        bool dpos  = disc > 0.0f;
        hit = hit | (dpos & (q1 > epsA) & (ax1A >= 0.0f) & (ax1A <= LA))
                  | (dpos & (q2 > epsA) & (ax2A >= 0.0f) & (ax2A <= LA));
    }

    // Boxes — branchless slab test.
    {
        float ivx = frcp((fabsf(ux) < FEPS) ? FEPS : ux);
        float ivy = frcp((fabsf(uy) < FEPS) ? FEPS : uy);
        float ivz = frcp((fabsf(uz) < FEPS) ? FEPS : uz);
        #pragma unroll
        for (int b = 0; b < NBOX; b++) {
            float4 b1 = s_box[b][0];
            float4 b2 = s_box[b][1];
            float t0x = (b1.x - tpx) * ivx, t1x = (b2.x - tpx) * ivx;
            float t0y = (b1.y - tpy) * ivy, t1y = (b2.y - tpy) * ivy;
            float t0z = (b1.z - tpz) * ivz, t1z = (b2.z - tpz) * ivz;
            float tmin = fmaxf(fmaxf(fminf(t0x,t1x), fminf(t0y,t1y)), fminf(t0z,t1z));
            float tmax = fminf(fminf(fmaxf(t0x,t1x), fmaxf(t0y,t1y)), fmaxf(t0z,t1z));
            hit = hit | (tmax >= fmaxf(tmin, FEPS));
        }
    }

    // Epilogue: reflect, project, scatter.
    {
        float dn = dx*tnx + dy*tny + dz*tnz;
        float rx = fmaf(-2.0f*dn, tnx, dx);
        float ry = fmaf(-2.0f*dn, tny, dy);
        float rz = fmaf(-2.0f*dn, tnz, dz);
        float cosv  = fabsf(dn);
        float denom = rx*spnx + ry*spny + rz*spnz;
        float num   = (sppx-tpx)*spnx + (sppy-tpy)*spny + (sppz-tpz)*spnz;
        float tt = num * frcp(denom + FEPS);
        float qx = fmaf(tt, rx, tpx);
        float qy = fmaf(tt, ry, tpy);
        float fx = (qx + FEXT) * PXSCALE;
        float fy = (qy + FEXT) * PXSCALE;
        float fxf = floorf(fx), fyf = floorf(fy);
        bool inb = (fxf >= 0.0f) & (fxf < (float)IW) & (fyf >= 0.0f) & (fyf < (float)IH)
                   & (!hit);
        if (inb) {
            atomicAdd(&img[(int)fyf * IW + (int)fxf], cosv);
        }
    }
}

extern "C" void kernel_launch(void* const* d_in, const int* in_sizes, int n_in,
                              void* d_out, int out_size, void* d_ws, size_t ws_size,
                              hipStream_t stream) {
    const float* sources = (const float*)d_in[0];
    const float* mpts    = (const float*)d_in[1];
    const float* mnrm    = (const float*)d_in[2];
    const float* mpos    = (const float*)d_in[3];
    const float* mrot    = (const float*)d_in[4];
    const float* cp1     = (const float*)d_in[5];
    const float* cp2     = (const float*)d_in[6];
    const float* crad    = (const float*)d_in[7];
    const float* bp1     = (const float*)d_in[8];
    const float* bp2     = (const float*)d_in[9];
    const float* spp     = (const float*)d_in[10];
    const float* spn     = (const float*)d_in[11];

    float* img = (float*)d_out;  // fp32 accumulator IS the output
    hipMemsetAsync(img, 0, (size_t)IH * IW * sizeof(float), stream);

    dim3 grid(NP / 256, NS, NM);  // (8, 128, 64) = 65536 blocks, 1 ray/thread
    render_kernel<<<grid, 256, 0, stream>>>(sources, mpts, mnrm, mpos, mrot,
                                            cp1, cp2, crad, bp1, bp2, spp, spn, img);
}

// Round 6
// 881.900 us; speedup vs baseline: 1.1844x; 1.0851x over previous
//
#include <hip/hip_runtime.h>

// S,P,M=(128,2048,64), NC,NB=(16,8), H,W=512, EXTENT=12, EPS=1e-9
#define NS   128
#define NP   2048
#define NM   64
#define NCYL 16
#define NBOX 8
#define IH   512
#define IW   512
#define FEXT 12.0f
#define FEPS 1e-9f
#define PXSCALE ((float)IW / (2.0f * FEXT))
#define PRUNE_MARGIN 0.05f

__device__ __forceinline__ float frcp(float x)   { return __builtin_amdgcn_rcpf(x); }
__device__ __forceinline__ float frsq(float x)   { return __builtin_amdgcn_rsqf(x); }
__device__ __forceinline__ float fsqrt_(float x) { return __builtin_amdgcn_sqrtf(x); }
__device__ __forceinline__ float clamp01(float x){ return fminf(fmaxf(x, 0.0f), 1.0f); }

// ---------------- Pre-pass A: per-mirror bounding sphere of transformed points
__global__ __launch_bounds__(256) void mirror_bounds_kernel(
    const float* __restrict__ mpts, const float* __restrict__ mpos,
    const float* __restrict__ mrot, float4* __restrict__ bounds)
{
    const int m = blockIdx.x;
    const int t = threadIdx.x;
    float R0 = mrot[m*9+0], R1 = mrot[m*9+1], R2 = mrot[m*9+2];
    float R3 = mrot[m*9+3], R4 = mrot[m*9+4], R5 = mrot[m*9+5];
    float R6 = mrot[m*9+6], R7 = mrot[m*9+7], R8 = mrot[m*9+8];
    float posx = mpos[m*3+0], posy = mpos[m*3+1], posz = mpos[m*3+2];

    float mnx = 1e30f, mny = 1e30f, mnz = 1e30f;
    float mxx = -1e30f, mxy = -1e30f, mxz = -1e30f;
    for (int i = t; i < NP; i += 256) {
        long id = ((long)m * NP + i) * 3;
        float px = mpts[id+0], py = mpts[id+1], pz = mpts[id+2];
        float tx = R0*px + R1*py + R2*pz + posx;
        float ty = R3*px + R4*py + R5*pz + posy;
        float tz = R6*px + R7*py + R8*pz + posz;
        mnx = fminf(mnx, tx); mny = fminf(mny, ty); mnz = fminf(mnz, tz);
        mxx = fmaxf(mxx, tx); mxy = fmaxf(mxy, ty); mxz = fmaxf(mxz, tz);
    }
    __shared__ float red[6][256];
    red[0][t] = mnx; red[1][t] = mny; red[2][t] = mnz;
    red[3][t] = mxx; red[4][t] = mxy; red[5][t] = mxz;
    __syncthreads();
    for (int off = 128; off > 0; off >>= 1) {
        if (t < off) {
            red[0][t] = fminf(red[0][t], red[0][t+off]);
            red[1][t] = fminf(red[1][t], red[1][t+off]);
            red[2][t] = fminf(red[2][t], red[2][t+off]);
            red[3][t] = fmaxf(red[3][t], red[3][t+off]);
            red[4][t] = fmaxf(red[4][t], red[4][t+off]);
            red[5][t] = fmaxf(red[5][t], red[5][t+off]);
        }
        __syncthreads();
    }
    if (t == 0) {
        float cx = 0.5f*(red[0][0]+red[3][0]);
        float cy = 0.5f*(red[1][0]+red[4][0]);
        float cz = 0.5f*(red[2][0]+red[5][0]);
        float hx = 0.5f*(red[3][0]-red[0][0]);
        float hy = 0.5f*(red[4][0]-red[1][0]);
        float hz = 0.5f*(red[5][0]-red[2][0]);
        float r  = sqrtf(hx*hx + hy*hy + hz*hz);
        bounds[m] = make_float4(cx, cy, cz, r);
    }
}

// ---------------- Pre-pass B: per-(mirror,source) occluder mask (conservative)
__global__ __launch_bounds__(256) void mask_kernel(
    const float* __restrict__ sources,
    const float* __restrict__ cp1g, const float* __restrict__ cp2g,
    const float* __restrict__ crad,
    const float* __restrict__ bp1g, const float* __restrict__ bp2g,
    const float4* __restrict__ bounds, unsigned* __restrict__ masks)
{
    int pair = blockIdx.x * 256 + threadIdx.x;
    if (pair >= NM * NS) return;
    int m = pair / NS;
    int s = pair - m * NS;

    float4 bd = bounds[m];
    float cx = bd.x, cy = bd.y, cz = bd.z;
    float rm = bd.w + PRUNE_MARGIN;
    float sx = sources[s*3+0], sy = sources[s*3+1], sz = sources[s*3+2];

    // seg1 = [c_m, source]
    float d1x = sx - cx, d1y = sy - cy, d1z = sz - cz;
    float a = d1x*d1x + d1y*d1y + d1z*d1z;     // > 0 (|.| ~ 100)

    unsigned mask = 0;

    for (int c = 0; c < NCYL; c++) {
        float p2x = cp1g[c*3+0], p2y = cp1g[c*3+1], p2z = cp1g[c*3+2];
        float d2x = cp2g[c*3+0] - p2x, d2y = cp2g[c*3+1] - p2y, d2z = cp2g[c*3+2] - p2z;
        float rx = cx - p2x, ry = cy - p2y, rz = cz - p2z;
        float e = d2x*d2x + d2y*d2y + d2z*d2z;  // axis len^2 > 0
        float f = d2x*rx + d2y*ry + d2z*rz;
        float cc = d1x*rx + d1y*ry + d1z*rz;
        float b = d1x*d2x + d1y*d2y + d1z*d2z;
        float denom = a*e - b*b;
        float sN = (denom > 1e-6f) ? clamp01((b*f - cc*e) / denom) : 0.0f;
        float tN = (b*sN + f) / e;
        if (tN < 0.0f)      { tN = 0.0f; sN = clamp01(-cc / a); }
        else if (tN > 1.0f) { tN = 1.0f; sN = clamp01((b - cc) / a); }
        float gx = (cx + d1x*sN) - (p2x + d2x*tN);
        float gy = (cy + d1y*sN) - (p2y + d2y*tN);
        float gz = (cz + d1z*sN) - (p2z + d2z*tN);
        float dist2 = gx*gx + gy*gy + gz*gz;
        float thr = crad[c] + rm;
        if (dist2 <= thr*thr) mask |= (1u << c);
    }

    // segment [c_m, source] (t in [0,1]) vs AABB expanded by rm
    float ivx = 1.0f / ((fabsf(d1x) < FEPS) ? FEPS : d1x);
    float ivy = 1.0f / ((fabsf(d1y) < FEPS) ? FEPS : d1y);
    float ivz = 1.0f / ((fabsf(d1z) < FEPS) ? FEPS : d1z);
    for (int b = 0; b < NBOX; b++) {
        float lx = bp1g[b*3+0] - rm, ly = bp1g[b*3+1] - rm, lz = bp1g[b*3+2] - rm;
        float hx = bp2g[b*3+0] + rm, hy = bp2g[b*3+1] + rm, hz = bp2g[b*3+2] + rm;
        float t0x = (lx - cx) * ivx, t1x = (hx - cx) * ivx;
        float t0y = (ly - cy) * ivy, t1y = (hy - cy) * ivy;
        float t0z = (lz - cz) * ivz, t1z = (hz - cz) * ivz;
        float tmin = fmaxf(fmaxf(fminf(t0x,t1x), fminf(t0y,t1y)), fminf(t0z,t1z));
        float tmax = fminf(fminf(fmaxf(t0x,t1x), fmaxf(t0y,t1y)), fmaxf(t0z,t1z));
        if (fmaxf(tmin, 0.0f) <= fminf(tmax, 1.0f)) mask |= (1u << (16 + b));
    }

    masks[pair] = mask;
}

// ---------------- Main render kernel (mask-driven occlusion)
__global__ __launch_bounds__(256) void render_kernel(
    const float* __restrict__ sources, const float* __restrict__ mpts,
    const float* __restrict__ mnrm,    const float* __restrict__ mpos,
    const float* __restrict__ mrot,
    const float* __restrict__ cp1g, const float* __restrict__ cp2g,
    const float* __restrict__ crad, const float* __restrict__ bp1g,
    const float* __restrict__ bp2g, const float* __restrict__ spp,
    const float* __restrict__ spn,  const unsigned* __restrict__ masks,
    float* __restrict__ img)
{
    __shared__ float4 s_cyl[NCYL][2];
    __shared__ float4 s_box[NBOX][2];

    const int t = threadIdx.x;
    const int n = blockIdx.x * 256 + t;   // point index
    const int s = blockIdx.y;             // source index
    const int m = blockIdx.z;             // mirror index

    const long idx = ((long)m * NP + n) * 3;
    float px = mpts[idx+0], py = mpts[idx+1], pz = mpts[idx+2];
    float nx = mnrm[idx+0], ny = mnrm[idx+1], nz = mnrm[idx+2];

    if (t < NCYL) {
        float p1x = cp1g[t*3+0], p1y = cp1g[t*3+1], p1z = cp1g[t*3+2];
        float axx = cp2g[t*3+0] - p1x;
        float axy = cp2g[t*3+1] - p1y;
        float axz = cp2g[t*3+2] - p1z;
        float L   = sqrtf(axx*axx + axy*axy + axz*axz);
        float inv = 1.0f / (L + FEPS);
        float r   = crad[t];
        s_cyl[t][0] = make_float4(p1x, p1y, p1z, L);
        s_cyl[t][1] = make_float4(axx*inv, axy*inv, axz*inv, r*r);
    } else if (t < NCYL + NBOX) {
        int b = t - NCYL;
        s_box[b][0] = make_float4(bp1g[b*3+0], bp1g[b*3+1], bp1g[b*3+2], 0.0f);
        s_box[b][1] = make_float4(bp2g[b*3+0], bp2g[b*3+1], bp2g[b*3+2], 0.0f);
    }
    __syncthreads();

    float R0 = mrot[m*9+0], R1 = mrot[m*9+1], R2 = mrot[m*9+2];
    float R3 = mrot[m*9+3], R4 = mrot[m*9+4], R5 = mrot[m*9+5];
    float R6 = mrot[m*9+6], R7 = mrot[m*9+7], R8 = mrot[m*9+8];
    float posx = mpos[m*3+0], posy = mpos[m*3+1], posz = mpos[m*3+2];
    float sx = sources[s*3+0], sy = sources[s*3+1], sz = sources[s*3+2];
    float sppx = spp[0], sppy = spp[1], sppz = spp[2];
    float spnx = spn[0], spny = spn[1], spnz = spn[2];

    float tpx = R0*px + R1*py + R2*pz + posx;
    float tpy = R3*px + R4*py + R5*pz + posy;
    float tpz = R6*px + R7*py + R8*pz + posz;
    float tnx = R0*nx + R1*ny + R2*nz;
    float tny = R3*nx + R4*ny + R5*nz;
    float tnz = R6*nx + R7*ny + R8*nz;

    float dx = tpx - sx, dy = tpy - sy, dz = tpz - sz;
    float il = frsq(dx*dx + dy*dy + dz*dz);
    dx *= il; dy *= il; dz *= il;
    float ux = -dx, uy = -dy, uz = -dz;

    unsigned pm = masks[(unsigned)m * NS + (unsigned)s];
    pm = __builtin_amdgcn_readfirstlane(pm);   // force SGPR -> uniform scalar loops
    unsigned cmask = pm & 0xFFFFu;
    unsigned bmask = (pm >> 16) & 0xFFu;

    bool hit = false;

    // Cylinders in mask — division-free quadric (|u|=1, |a|=1).
    while (cmask) {
        int c = __builtin_ctz(cmask);
        cmask &= cmask - 1;
        float4 c0 = s_cyl[c][0];   // p1, L
        float4 c1 = s_cyl[c][1];   // a, r^2
        float ocx = tpx - c0.x, ocy = tpy - c0.y, ocz = tpz - c0.z;
        float oa  = ocx*c1.x + ocy*c1.y + ocz*c1.z;
        float Cc  = ocx*ocx + ocy*ocy + ocz*ocz - oa*oa - c1.w;
        float ua  = ux*c1.x + uy*c1.y + uz*c1.z;
        float ocu = ux*ocx + uy*ocy + uz*ocz;
        float Bh  = fmaf(-oa, ua, ocu);
        float A   = fmaf(-ua, ua, 1.0f);
        float disc = fmaf(Bh, Bh, -(A*Cc));
        float sq   = fsqrt_(fmaxf(disc, 0.0f));
        float Ah   = A + 0.5f*FEPS;
        float q1   = -Bh - sq;
        float q2   = -Bh + sq;
        float oaA  = oa * Ah;
        float LA   = c0.w * Ah;
        float epsA = FEPS * Ah;
        float ax1A = fmaf(q1, ua, oaA);
        float ax2A = fmaf(q2, ua, oaA);
        bool dpos  = disc > 0.0f;
        hit = hit | (dpos & (q1 > epsA) & (ax1A >= 0.0f) & (ax1A <= LA))
                  | (dpos & (q2 > epsA) & (ax2A >= 0.0f) & (ax2A <= LA));
    }

    if (bmask) {
        float ivx = frcp((fabsf(ux) < FEPS) ? FEPS : ux);
        float ivy = frcp((fabsf(uy) < FEPS) ? FEPS : uy);
        float ivz = frcp((fabsf(uz) < FEPS) ? FEPS : uz);
        while (bmask) {
            int b = __builtin_ctz(bmask);
            bmask &= bmask - 1;
            float4 b1 = s_box[b][0];
            float4 b2 = s_box[b][1];
            float t0x = (b1.x - tpx) * ivx, t1x = (b2.x - tpx) * ivx;
            float t0y = (b1.y - tpy) * ivy, t1y = (b2.y - tpy) * ivy;
            float t0z = (b1.z - tpz) * ivz, t1z = (b2.z - tpz) * ivz;
            float tmin = fmaxf(fmaxf(fminf(t0x,t1x), fminf(t0y,t1y)), fminf(t0z,t1z));
            float tmax = fminf(fminf(fmaxf(t0x,t1x), fmaxf(t0y,t1y)), fmaxf(t0z,t1z));
            hit = hit | (tmax >= fmaxf(tmin, FEPS));
        }
    }

    // Epilogue: reflect, project, scatter.
    {
        float dn = dx*tnx + dy*tny + dz*tnz;
        float rx = fmaf(-2.0f*dn, tnx, dx);
        float ry = fmaf(-2.0f*dn, tny, dy);
        float rz = fmaf(-2.0f*dn, tnz, dz);
        float cosv  = fabsf(dn);
        float denom = rx*spnx + ry*spny + rz*spnz;
        float num   = (sppx-tpx)*spnx + (sppy-tpy)*spny + (sppz-tpz)*spnz;
        float tt = num * frcp(denom + FEPS);
        float qx = fmaf(tt, rx, tpx);
        float qy = fmaf(tt, ry, tpy);
        float fx = (qx + FEXT) * PXSCALE;
        float fy = (qy + FEXT) * PXSCALE;
        float fxf = floorf(fx), fyf = floorf(fy);
        bool inb = (fxf >= 0.0f) & (fxf < (float)IW) & (fyf >= 0.0f) & (fyf < (float)IH)
                   & (!hit);
        if (inb) {
            atomicAdd(&img[(int)fyf * IW + (int)fxf], cosv);
        }
    }
}

extern "C" void kernel_launch(void* const* d_in, const int* in_sizes, int n_in,
                              void* d_out, int out_size, void* d_ws, size_t ws_size,
                              hipStream_t stream) {
    const float* sources = (const float*)d_in[0];
    const float* mpts    = (const float*)d_in[1];
    const float* mnrm    = (const float*)d_in[2];
    const float* mpos    = (const float*)d_in[3];
    const float* mrot    = (const float*)d_in[4];
    const float* cp1     = (const float*)d_in[5];
    const float* cp2     = (const float*)d_in[6];
    const float* crad    = (const float*)d_in[7];
    const float* bp1     = (const float*)d_in[8];
    const float* bp2     = (const float*)d_in[9];
    const float* spp     = (const float*)d_in[10];
    const float* spn     = (const float*)d_in[11];

    float*    img    = (float*)d_out;               // output accumulator
    float4*   bounds = (float4*)d_ws;               // 64 * 16 B = 1 KB
    unsigned* masks  = (unsigned*)((char*)d_ws + 1024);  // 8192 * 4 B = 32 KB

    hipMemsetAsync(img, 0, (size_t)IH * IW * sizeof(float), stream);

    mirror_bounds_kernel<<<NM, 256, 0, stream>>>(mpts, mpos, mrot, bounds);
    mask_kernel<<<(NM * NS + 255) / 256, 256, 0, stream>>>(
        sources, cp1, cp2, crad, bp1, bp2, bounds, masks);

    dim3 grid(NP / 256, NS, NM);  // (8, 128, 64), 1 ray/thread
    render_kernel<<<grid, 256, 0, stream>>>(sources, mpts, mnrm, mpos, mrot,
                                            cp1, cp2, crad, bp1, bp2, spp, spn,
                                            masks, img);
}

// Round 7
// 758.984 us; speedup vs baseline: 1.3762x; 1.1619x over previous
//
#include <hip/hip_runtime.h>

// S,P,M=(128,2048,64), NC,NB=(16,8), H,W=512, EXTENT=12, EPS=1e-9
#define NS   128
#define NP   2048
#define NM   64
#define NCYL 16
#define NBOX 8
#define IH   512
#define IW   512
#define NPIX (IH*IW)
#define FEXT 12.0f
#define FEPS 1e-9f
#define PXSCALE ((float)IW / (2.0f * FEXT))
#define PRUNE_MARGIN 0.05f
#define SPT  8   // sources per thread (sequential loop: reuse tp/tn, pipeline atomics)

__device__ __forceinline__ float frcp(float x)   { return __builtin_amdgcn_rcpf(x); }
__device__ __forceinline__ float frsq(float x)   { return __builtin_amdgcn_rsqf(x); }
__device__ __forceinline__ float fsqrt_(float x) { return __builtin_amdgcn_sqrtf(x); }
__device__ __forceinline__ float clamp01(float x){ return fminf(fmaxf(x, 0.0f), 1.0f); }

// ---------------- Pre-pass A: per-mirror bounding sphere of transformed points
__global__ __launch_bounds__(256) void mirror_bounds_kernel(
    const float* __restrict__ mpts, const float* __restrict__ mpos,
    const float* __restrict__ mrot, float4* __restrict__ bounds)
{
    const int m = blockIdx.x;
    const int t = threadIdx.x;
    float R0 = mrot[m*9+0], R1 = mrot[m*9+1], R2 = mrot[m*9+2];
    float R3 = mrot[m*9+3], R4 = mrot[m*9+4], R5 = mrot[m*9+5];
    float R6 = mrot[m*9+6], R7 = mrot[m*9+7], R8 = mrot[m*9+8];
    float posx = mpos[m*3+0], posy = mpos[m*3+1], posz = mpos[m*3+2];

    float mnx = 1e30f, mny = 1e30f, mnz = 1e30f;
    float mxx = -1e30f, mxy = -1e30f, mxz = -1e30f;
    for (int i = t; i < NP; i += 256) {
        long id = ((long)m * NP + i) * 3;
        float px = mpts[id+0], py = mpts[id+1], pz = mpts[id+2];
        float tx = R0*px + R1*py + R2*pz + posx;
        float ty = R3*px + R4*py + R5*pz + posy;
        float tz = R6*px + R7*py + R8*pz + posz;
        mnx = fminf(mnx, tx); mny = fminf(mny, ty); mnz = fminf(mnz, tz);
        mxx = fmaxf(mxx, tx); mxy = fmaxf(mxy, ty); mxz = fmaxf(mxz, tz);
    }
    __shared__ float red[6][256];
    red[0][t] = mnx; red[1][t] = mny; red[2][t] = mnz;
    red[3][t] = mxx; red[4][t] = mxy; red[5][t] = mxz;
    __syncthreads();
    for (int off = 128; off > 0; off >>= 1) {
        if (t < off) {
            red[0][t] = fminf(red[0][t], red[0][t+off]);
            red[1][t] = fminf(red[1][t], red[1][t+off]);
            red[2][t] = fminf(red[2][t], red[2][t+off]);
            red[3][t] = fmaxf(red[3][t], red[3][t+off]);
            red[4][t] = fmaxf(red[4][t], red[4][t+off]);
            red[5][t] = fmaxf(red[5][t], red[5][t+off]);
        }
        __syncthreads();
    }
    if (t == 0) {
        float cx = 0.5f*(red[0][0]+red[3][0]);
        float cy = 0.5f*(red[1][0]+red[4][0]);
        float cz = 0.5f*(red[2][0]+red[5][0]);
        float hx = 0.5f*(red[3][0]-red[0][0]);
        float hy = 0.5f*(red[4][0]-red[1][0]);
        float hz = 0.5f*(red[5][0]-red[2][0]);
        float r  = sqrtf(hx*hx + hy*hy + hz*hz);
        bounds[m] = make_float4(cx, cy, cz, r);
    }
}

// ---------------- Pre-pass B: per-(mirror,source) occluder mask (conservative)
__global__ __launch_bounds__(256) void mask_kernel(
    const float* __restrict__ sources,
    const float* __restrict__ cp1g, const float* __restrict__ cp2g,
    const float* __restrict__ crad,
    const float* __restrict__ bp1g, const float* __restrict__ bp2g,
    const float4* __restrict__ bounds, unsigned* __restrict__ masks)
{
    int pair = blockIdx.x * 256 + threadIdx.x;
    if (pair >= NM * NS) return;
    int m = pair / NS;
    int s = pair - m * NS;

    float4 bd = bounds[m];
    float cx = bd.x, cy = bd.y, cz = bd.z;
    float rm = bd.w + PRUNE_MARGIN;
    float sx = sources[s*3+0], sy = sources[s*3+1], sz = sources[s*3+2];

    float d1x = sx - cx, d1y = sy - cy, d1z = sz - cz;
    float a = d1x*d1x + d1y*d1y + d1z*d1z;

    unsigned mask = 0;

    for (int c = 0; c < NCYL; c++) {
        float p2x = cp1g[c*3+0], p2y = cp1g[c*3+1], p2z = cp1g[c*3+2];
        float d2x = cp2g[c*3+0] - p2x, d2y = cp2g[c*3+1] - p2y, d2z = cp2g[c*3+2] - p2z;
        float rx = cx - p2x, ry = cy - p2y, rz = cz - p2z;
        float e = d2x*d2x + d2y*d2y + d2z*d2z;
        float f = d2x*rx + d2y*ry + d2z*rz;
        float cc = d1x*rx + d1y*ry + d1z*rz;
        float b = d1x*d2x + d1y*d2y + d1z*d2z;
        float denom = a*e - b*b;
        float sN = (denom > 1e-6f) ? clamp01((b*f - cc*e) / denom) : 0.0f;
        float tN = (b*sN + f) / e;
        if (tN < 0.0f)      { tN = 0.0f; sN = clamp01(-cc / a); }
        else if (tN > 1.0f) { tN = 1.0f; sN = clamp01((b - cc) / a); }
        float gx = (cx + d1x*sN) - (p2x + d2x*tN);
        float gy = (cy + d1y*sN) - (p2y + d2y*tN);
        float gz = (cz + d1z*sN) - (p2z + d2z*tN);
        float dist2 = gx*gx + gy*gy + gz*gz;
        float thr = crad[c] + rm;
        if (dist2 <= thr*thr) mask |= (1u << c);
    }

    float ivx = 1.0f / ((fabsf(d1x) < FEPS) ? FEPS : d1x);
    float ivy = 1.0f / ((fabsf(d1y) < FEPS) ? FEPS : d1y);
    float ivz = 1.0f / ((fabsf(d1z) < FEPS) ? FEPS : d1z);
    for (int b = 0; b < NBOX; b++) {
        float lx = bp1g[b*3+0] - rm, ly = bp1g[b*3+1] - rm, lz = bp1g[b*3+2] - rm;
        float hx = bp2g[b*3+0] + rm, hy = bp2g[b*3+1] + rm, hz = bp2g[b*3+2] + rm;
        float t0x = (lx - cx) * ivx, t1x = (hx - cx) * ivx;
        float t0y = (ly - cy) * ivy, t1y = (hy - cy) * ivy;
        float t0z = (lz - cz) * ivz, t1z = (hz - cz) * ivz;
        float tmin = fmaxf(fmaxf(fminf(t0x,t1x), fminf(t0y,t1y)), fminf(t0z,t1z));
        float tmax = fminf(fminf(fmaxf(t0x,t1x), fmaxf(t0y,t1y)), fmaxf(t0z,t1z));
        if (fmaxf(tmin, 0.0f) <= fminf(tmax, 1.0f)) mask |= (1u << (16 + b));
    }

    masks[pair] = mask;
}

// ---------------- Main render: 8 sources/thread, K privatized images
__global__ __launch_bounds__(256) void render_kernel(
    const float* __restrict__ sources, const float* __restrict__ mpts,
    const float* __restrict__ mnrm,    const float* __restrict__ mpos,
    const float* __restrict__ mrot,
    const float* __restrict__ cp1g, const float* __restrict__ cp2g,
    const float* __restrict__ crad, const float* __restrict__ bp1g,
    const float* __restrict__ bp2g, const float* __restrict__ spp,
    const float* __restrict__ spn,  const unsigned* __restrict__ masks,
    float* __restrict__ imgs, int K)
{
    __shared__ float4 s_cyl[NCYL][2];
    __shared__ float4 s_box[NBOX][2];

    const int t  = threadIdx.x;
    const int n  = blockIdx.x * 256 + t;   // point index
    const int s0 = blockIdx.y * SPT;       // first source index
    const int m  = blockIdx.z;             // mirror index

    const long idx = ((long)m * NP + n) * 3;
    float px = mpts[idx+0], py = mpts[idx+1], pz = mpts[idx+2];
    float nx = mnrm[idx+0], ny = mnrm[idx+1], nz = mnrm[idx+2];

    if (t < NCYL) {
        float p1x = cp1g[t*3+0], p1y = cp1g[t*3+1], p1z = cp1g[t*3+2];
        float axx = cp2g[t*3+0] - p1x;
        float axy = cp2g[t*3+1] - p1y;
        float axz = cp2g[t*3+2] - p1z;
        float L   = sqrtf(axx*axx + axy*axy + axz*axz);
        float inv = 1.0f / (L + FEPS);
        float r   = crad[t];
        s_cyl[t][0] = make_float4(p1x, p1y, p1z, L);
        s_cyl[t][1] = make_float4(axx*inv, axy*inv, axz*inv, r*r);
    } else if (t < NCYL + NBOX) {
        int b = t - NCYL;
        s_box[b][0] = make_float4(bp1g[b*3+0], bp1g[b*3+1], bp1g[b*3+2], 0.0f);
        s_box[b][1] = make_float4(bp2g[b*3+0], bp2g[b*3+1], bp2g[b*3+2], 0.0f);
    }
    __syncthreads();

    float R0 = mrot[m*9+0], R1 = mrot[m*9+1], R2 = mrot[m*9+2];
    float R3 = mrot[m*9+3], R4 = mrot[m*9+4], R5 = mrot[m*9+5];
    float R6 = mrot[m*9+6], R7 = mrot[m*9+7], R8 = mrot[m*9+8];
    float posx = mpos[m*3+0], posy = mpos[m*3+1], posz = mpos[m*3+2];
    float sppx = spp[0], sppy = spp[1], sppz = spp[2];
    float spnx = spn[0], spny = spn[1], spnz = spn[2];

    float tpx = R0*px + R1*py + R2*pz + posx;
    float tpy = R3*px + R4*py + R5*pz + posy;
    float tpz = R6*px + R7*py + R8*pz + posz;
    float tnx = R0*nx + R1*ny + R2*nz;
    float tny = R3*nx + R4*ny + R5*nz;
    float tnz = R6*nx + R7*ny + R8*nz;

    float num = (sppx-tpx)*spnx + (sppy-tpy)*spny + (sppz-tpz)*spnz;  // src-invariant

    // Block-linear index -> partial image (contention spread across K images).
    int linb = blockIdx.x + (int)gridDim.x * (blockIdx.y + (int)gridDim.y * blockIdx.z);
    float* __restrict__ img = imgs + (size_t)(linb % K) * NPIX;

    for (int j = 0; j < SPT; j++) {
        const int s = s0 + j;
        float sx = sources[s*3+0], sy = sources[s*3+1], sz = sources[s*3+2];

        float dx = tpx - sx, dy = tpy - sy, dz = tpz - sz;
        float il = frsq(dx*dx + dy*dy + dz*dz);
        dx *= il; dy *= il; dz *= il;
        float ux = -dx, uy = -dy, uz = -dz;

        unsigned pm = masks[(unsigned)m * NS + (unsigned)s];
        pm = __builtin_amdgcn_readfirstlane(pm);
        unsigned cmask = pm & 0xFFFFu;
        unsigned bmask = (pm >> 16) & 0xFFu;

        bool hit = false;

        while (cmask) {
            int c = __builtin_ctz(cmask);
            cmask &= cmask - 1;
            float4 c0 = s_cyl[c][0];   // p1, L
            float4 c1 = s_cyl[c][1];   // a, r^2
            float ocx = tpx - c0.x, ocy = tpy - c0.y, ocz = tpz - c0.z;
            float oa  = ocx*c1.x + ocy*c1.y + ocz*c1.z;
            float Cc  = ocx*ocx + ocy*ocy + ocz*ocz - oa*oa - c1.w;
            float ua  = ux*c1.x + uy*c1.y + uz*c1.z;
            float ocu = ux*ocx + uy*ocy + uz*ocz;
            float Bh  = fmaf(-oa, ua, ocu);
            float A   = fmaf(-ua, ua, 1.0f);
            float disc = fmaf(Bh, Bh, -(A*Cc));
            float sq   = fsqrt_(fmaxf(disc, 0.0f));
            float Ah   = A + 0.5f*FEPS;
            float q1   = -Bh - sq;
            float q2   = -Bh + sq;
            float oaA  = oa * Ah;
            float LA   = c0.w * Ah;
            float epsA = FEPS * Ah;
            float ax1A = fmaf(q1, ua, oaA);
            float ax2A = fmaf(q2, ua, oaA);
            bool dpos  = disc > 0.0f;
            hit = hit | (dpos & (q1 > epsA) & (ax1A >= 0.0f) & (ax1A <= LA))
                      | (dpos & (q2 > epsA) & (ax2A >= 0.0f) & (ax2A <= LA));
        }

        if (bmask) {
            float ivx = frcp((fabsf(ux) < FEPS) ? FEPS : ux);
            float ivy = frcp((fabsf(uy) < FEPS) ? FEPS : uy);
            float ivz = frcp((fabsf(uz) < FEPS) ? FEPS : uz);
            while (bmask) {
                int b = __builtin_ctz(bmask);
                bmask &= bmask - 1;
                float4 b1 = s_box[b][0];
                float4 b2 = s_box[b][1];
                float t0x = (b1.x - tpx) * ivx, t1x = (b2.x - tpx) * ivx;
                float t0y = (b1.y - tpy) * ivy, t1y = (b2.y - tpy) * ivy;
                float t0z = (b1.z - tpz) * ivz, t1z = (b2.z - tpz) * ivz;
                float tmin = fmaxf(fmaxf(fminf(t0x,t1x), fminf(t0y,t1y)), fminf(t0z,t1z));
                float tmax = fminf(fminf(fmaxf(t0x,t1x), fmaxf(t0y,t1y)), fmaxf(t0z,t1z));
                hit = hit | (tmax >= fmaxf(tmin, FEPS));
            }
        }

        {
            float dn = dx*tnx + dy*tny + dz*tnz;
            float rx = fmaf(-2.0f*dn, tnx, dx);
            float ry = fmaf(-2.0f*dn, tny, dy);
            float rz = fmaf(-2.0f*dn, tnz, dz);
            float cosv  = fabsf(dn);
            float denom = rx*spnx + ry*spny + rz*spnz;
            float tt = num * frcp(denom + FEPS);
            float qx = fmaf(tt, rx, tpx);
            float qy = fmaf(tt, ry, tpy);
            float fx = (qx + FEXT) * PXSCALE;
            float fy = (qy + FEXT) * PXSCALE;
            float fxf = floorf(fx), fyf = floorf(fy);
            bool inb = (fxf >= 0.0f) & (fxf < (float)IW) & (fyf >= 0.0f) & (fyf < (float)IH)
                       & (!hit);
            if (inb) {
                atomicAdd(&img[(int)fyf * IW + (int)fxf], cosv);  // fire-and-forget; pipelines across j
            }
        }
    }
}

// ---------------- Reduce: sum K partial images into d_out
__global__ __launch_bounds__(256) void reduce_kernel(
    const float* __restrict__ imgs, int K, float* __restrict__ out)
{
    int i = blockIdx.x * 256 + threadIdx.x;
    float v = 0.0f;
    for (int k = 0; k < K; k++) v += imgs[(size_t)k * NPIX + i];
    out[i] = v;
}

extern "C" void kernel_launch(void* const* d_in, const int* in_sizes, int n_in,
                              void* d_out, int out_size, void* d_ws, size_t ws_size,
                              hipStream_t stream) {
    const float* sources = (const float*)d_in[0];
    const float* mpts    = (const float*)d_in[1];
    const float* mnrm    = (const float*)d_in[2];
    const float* mpos    = (const float*)d_in[3];
    const float* mrot    = (const float*)d_in[4];
    const float* cp1     = (const float*)d_in[5];
    const float* cp2     = (const float*)d_in[6];
    const float* crad    = (const float*)d_in[7];
    const float* bp1     = (const float*)d_in[8];
    const float* bp2     = (const float*)d_in[9];
    const float* spp     = (const float*)d_in[10];
    const float* spn     = (const float*)d_in[11];

    const size_t IMG_BYTES = (size_t)NPIX * sizeof(float);
    const size_t AUX_BYTES = 1024 + (size_t)NM * NS * sizeof(unsigned);  // bounds + masks

    // Choose K partial images that fit in ws (power of 2, up to 8).
    int K = 0;
    for (int k = 8; k >= 1; k >>= 1) {
        if ((size_t)k * IMG_BYTES + AUX_BYTES <= ws_size) { K = k; break; }
    }

    float*    imgs;
    char*     aux;
    if (K >= 1) {
        imgs = (float*)d_ws;
        aux  = (char*)d_ws + (size_t)K * IMG_BYTES;
        hipMemsetAsync(imgs, 0, (size_t)K * IMG_BYTES, stream);
    } else {
        // Fallback: accumulate directly in d_out (previous behavior).
        K    = 1;
        imgs = (float*)d_out;
        aux  = (char*)d_ws;
        hipMemsetAsync(imgs, 0, IMG_BYTES, stream);
    }
    float4*   bounds = (float4*)aux;
    unsigned* masks  = (unsigned*)(aux + 1024);

    mirror_bounds_kernel<<<NM, 256, 0, stream>>>(mpts, mpos, mrot, bounds);
    mask_kernel<<<(NM * NS + 255) / 256, 256, 0, stream>>>(
        sources, cp1, cp2, crad, bp1, bp2, bounds, masks);

    dim3 grid(NP / 256, NS / SPT, NM);  // (8, 16, 64) = 8192 blocks
    render_kernel<<<grid, 256, 0, stream>>>(sources, mpts, mnrm, mpos, mrot,
                                            cp1, cp2, crad, bp1, bp2, spp, spn,
                                            masks, imgs, K);

    if (imgs != (float*)d_out) {
        reduce_kernel<<<NPIX / 256, 256, 0, stream>>>(imgs, K, (float*)d_out);
    }
}

// Round 8
// 588.692 us; speedup vs baseline: 1.7744x; 1.2893x over previous
//
#include <hip/hip_runtime.h>

// S,P,M=(128,2048,64), NC,NB=(16,8), H,W=512, EXTENT=12, EPS=1e-9
#define NS   128
#define NP   2048
#define NM   64
#define NCYL 16
#define NBOX 8
#define IH   512
#define IW   512
#define NPIX (IH*IW)
#define FEXT 12.0f
#define FEPS 1e-9f
#define PXSCALE ((float)IW / (2.0f * FEXT))
#define PRUNE_MARGIN 0.05f
#define SPT  8      // sources per thread
#define NTILE 256   // 16x16 grid of 32x32-pixel tiles
#define MAXD  4096  // descriptor slots per tile
#define GSPLIT 8    // pass-2 blocks per tile

__device__ __forceinline__ float frcp(float x)   { return __builtin_amdgcn_rcpf(x); }
__device__ __forceinline__ float frsq(float x)   { return __builtin_amdgcn_rsqf(x); }
__device__ __forceinline__ float fsqrt_(float x) { return __builtin_amdgcn_sqrtf(x); }
__device__ __forceinline__ float clamp01(float x){ return fminf(fmaxf(x, 0.0f), 1.0f); }

// ---------------- Pre-pass A: per-mirror bounding sphere of transformed points
__global__ __launch_bounds__(256) void mirror_bounds_kernel(
    const float* __restrict__ mpts, const float* __restrict__ mpos,
    const float* __restrict__ mrot, float4* __restrict__ bounds)
{
    const int m = blockIdx.x;
    const int t = threadIdx.x;
    float R0 = mrot[m*9+0], R1 = mrot[m*9+1], R2 = mrot[m*9+2];
    float R3 = mrot[m*9+3], R4 = mrot[m*9+4], R5 = mrot[m*9+5];
    float R6 = mrot[m*9+6], R7 = mrot[m*9+7], R8 = mrot[m*9+8];
    float posx = mpos[m*3+0], posy = mpos[m*3+1], posz = mpos[m*3+2];

    float mnx = 1e30f, mny = 1e30f, mnz = 1e30f;
    float mxx = -1e30f, mxy = -1e30f, mxz = -1e30f;
    for (int i = t; i < NP; i += 256) {
        long id = ((long)m * NP + i) * 3;
        float px = mpts[id+0], py = mpts[id+1], pz = mpts[id+2];
        float tx = R0*px + R1*py + R2*pz + posx;
        float ty = R3*px + R4*py + R5*pz + posy;
        float tz = R6*px + R7*py + R8*pz + posz;
        mnx = fminf(mnx, tx); mny = fminf(mny, ty); mnz = fminf(mnz, tz);
        mxx = fmaxf(mxx, tx); mxy = fmaxf(mxy, ty); mxz = fmaxf(mxz, tz);
    }
    __shared__ float red[6][256];
    red[0][t] = mnx; red[1][t] = mny; red[2][t] = mnz;
    red[3][t] = mxx; red[4][t] = mxy; red[5][t] = mxz;
    __syncthreads();
    for (int off = 128; off > 0; off >>= 1) {
        if (t < off) {
            red[0][t] = fminf(red[0][t], red[0][t+off]);
            red[1][t] = fminf(red[1][t], red[1][t+off]);
            red[2][t] = fminf(red[2][t], red[2][t+off]);
            red[3][t] = fmaxf(red[3][t], red[3][t+off]);
            red[4][t] = fmaxf(red[4][t], red[4][t+off]);
            red[5][t] = fmaxf(red[5][t], red[5][t+off]);
        }
        __syncthreads();
    }
    if (t == 0) {
        float cx = 0.5f*(red[0][0]+red[3][0]);
        float cy = 0.5f*(red[1][0]+red[4][0]);
        float cz = 0.5f*(red[2][0]+red[5][0]);
        float hx = 0.5f*(red[3][0]-red[0][0]);
        float hy = 0.5f*(red[4][0]-red[1][0]);
        float hz = 0.5f*(red[5][0]-red[2][0]);
        float r  = sqrtf(hx*hx + hy*hy + hz*hz);
        bounds[m] = make_float4(cx, cy, cz, r);
    }
}

// ---------------- Pre-pass B: per-(mirror,source) occluder mask (conservative)
__global__ __launch_bounds__(256) void mask_kernel(
    const float* __restrict__ sources,
    const float* __restrict__ cp1g, const float* __restrict__ cp2g,
    const float* __restrict__ crad,
    const float* __restrict__ bp1g, const float* __restrict__ bp2g,
    const float4* __restrict__ bounds, unsigned* __restrict__ masks)
{
    int pair = blockIdx.x * 256 + threadIdx.x;
    if (pair >= NM * NS) return;
    int m = pair / NS;
    int s = pair - m * NS;

    float4 bd = bounds[m];
    float cx = bd.x, cy = bd.y, cz = bd.z;
    float rm = bd.w + PRUNE_MARGIN;
    float sx = sources[s*3+0], sy = sources[s*3+1], sz = sources[s*3+2];

    float d1x = sx - cx, d1y = sy - cy, d1z = sz - cz;
    float a = d1x*d1x + d1y*d1y + d1z*d1z;

    unsigned mask = 0;

    for (int c = 0; c < NCYL; c++) {
        float p2x = cp1g[c*3+0], p2y = cp1g[c*3+1], p2z = cp1g[c*3+2];
        float d2x = cp2g[c*3+0] - p2x, d2y = cp2g[c*3+1] - p2y, d2z = cp2g[c*3+2] - p2z;
        float rx = cx - p2x, ry = cy - p2y, rz = cz - p2z;
        float e = d2x*d2x + d2y*d2y + d2z*d2z;
        float f = d2x*rx + d2y*ry + d2z*rz;
        float cc = d1x*rx + d1y*ry + d1z*rz;
        float b = d1x*d2x + d1y*d2y + d1z*d2z;
        float denom = a*e - b*b;
        float sN = (denom > 1e-6f) ? clamp01((b*f - cc*e) / denom) : 0.0f;
        float tN = (b*sN + f) / e;
        if (tN < 0.0f)      { tN = 0.0f; sN = clamp01(-cc / a); }
        else if (tN > 1.0f) { tN = 1.0f; sN = clamp01((b - cc) / a); }
        float gx = (cx + d1x*sN) - (p2x + d2x*tN);
        float gy = (cy + d1y*sN) - (p2y + d2y*tN);
        float gz = (cz + d1z*sN) - (p2z + d2z*tN);
        float dist2 = gx*gx + gy*gy + gz*gz;
        float thr = crad[c] + rm;
        if (dist2 <= thr*thr) mask |= (1u << c);
    }

    float ivx = 1.0f / ((fabsf(d1x) < FEPS) ? FEPS : d1x);
    float ivy = 1.0f / ((fabsf(d1y) < FEPS) ? FEPS : d1y);
    float ivz = 1.0f / ((fabsf(d1z) < FEPS) ? FEPS : d1z);
    for (int b = 0; b < NBOX; b++) {
        float lx = bp1g[b*3+0] - rm, ly = bp1g[b*3+1] - rm, lz = bp1g[b*3+2] - rm;
        float hx = bp2g[b*3+0] + rm, hy = bp2g[b*3+1] + rm, hz = bp2g[b*3+2] + rm;
        float t0x = (lx - cx) * ivx, t1x = (hx - cx) * ivx;
        float t0y = (ly - cy) * ivy, t1y = (hy - cy) * ivy;
        float t0z = (lz - cz) * ivz, t1z = (hz - cz) * ivz;
        float tmin = fmaxf(fmaxf(fminf(t0x,t1x), fminf(t0y,t1y)), fminf(t0z,t1z));
        float tmax = fminf(fminf(fmaxf(t0x,t1x), fmaxf(t0y,t1y)), fmaxf(t0z,t1z));
        if (fmaxf(tmin, 0.0f) <= fminf(tmax, 1.0f)) mask |= (1u << (16 + b));
    }

    masks[pair] = mask;
}

// ================= BINNING PIPELINE (pass 1): rays -> tile-grouped records
__global__ __launch_bounds__(256) void render_bin_kernel(
    const float* __restrict__ sources, const float* __restrict__ mpts,
    const float* __restrict__ mnrm,    const float* __restrict__ mpos,
    const float* __restrict__ mrot,
    const float* __restrict__ cp1g, const float* __restrict__ cp2g,
    const float* __restrict__ crad, const float* __restrict__ bp1g,
    const float* __restrict__ bp2g, const float* __restrict__ spp,
    const float* __restrict__ spn,  const unsigned* __restrict__ masks,
    unsigned* __restrict__ arena, uint2* __restrict__ desc,
    unsigned* __restrict__ desc_cnt, unsigned* __restrict__ galloc,
    float* __restrict__ img_direct)
{
    __shared__ float4 s_cyl[NCYL][2];
    __shared__ float4 s_box[NBOX][2];
    __shared__ unsigned s_cnt[NTILE];
    __shared__ unsigned s_inc[NTILE];
    __shared__ unsigned s_scratch[256 * SPT];
    __shared__ unsigned s_base;

    const int t  = threadIdx.x;
    const int n  = blockIdx.x * 256 + t;
    const int s0 = blockIdx.y * SPT;
    const int m  = blockIdx.z;

    const long idx = ((long)m * NP + n) * 3;
    float px = mpts[idx+0], py = mpts[idx+1], pz = mpts[idx+2];
    float nx = mnrm[idx+0], ny = mnrm[idx+1], nz = mnrm[idx+2];

    s_cnt[t] = 0;   // 256 threads == NTILE
    if (t < NCYL) {
        float p1x = cp1g[t*3+0], p1y = cp1g[t*3+1], p1z = cp1g[t*3+2];
        float axx = cp2g[t*3+0] - p1x;
        float axy = cp2g[t*3+1] - p1y;
        float axz = cp2g[t*3+2] - p1z;
        float L   = sqrtf(axx*axx + axy*axy + axz*axz);
        float inv = 1.0f / (L + FEPS);
        float r   = crad[t];
        s_cyl[t][0] = make_float4(p1x, p1y, p1z, L);
        s_cyl[t][1] = make_float4(axx*inv, axy*inv, axz*inv, r*r);
    } else if (t < NCYL + NBOX) {
        int b = t - NCYL;
        s_box[b][0] = make_float4(bp1g[b*3+0], bp1g[b*3+1], bp1g[b*3+2], 0.0f);
        s_box[b][1] = make_float4(bp2g[b*3+0], bp2g[b*3+1], bp2g[b*3+2], 0.0f);
    }
    __syncthreads();

    float R0 = mrot[m*9+0], R1 = mrot[m*9+1], R2 = mrot[m*9+2];
    float R3 = mrot[m*9+3], R4 = mrot[m*9+4], R5 = mrot[m*9+5];
    float R6 = mrot[m*9+6], R7 = mrot[m*9+7], R8 = mrot[m*9+8];
    float posx = mpos[m*3+0], posy = mpos[m*3+1], posz = mpos[m*3+2];
    float sppx = spp[0], sppy = spp[1], sppz = spp[2];
    float spnx = spn[0], spny = spn[1], spnz = spn[2];

    float tpx = R0*px + R1*py + R2*pz + posx;
    float tpy = R3*px + R4*py + R5*pz + posy;
    float tpz = R6*px + R7*py + R8*pz + posz;
    float tnx = R0*nx + R1*ny + R2*nz;
    float tny = R3*nx + R4*ny + R5*nz;
    float tnz = R6*nx + R7*ny + R8*nz;

    float num = (sppx-tpx)*spnx + (sppy-tpy)*spny + (sppz-tpz)*spnz;

    unsigned rec[SPT];
    unsigned rank[SPT];
    int      tileid[SPT];
    unsigned vmask = 0;

    #pragma unroll
    for (int j = 0; j < SPT; j++) {
        const int s = s0 + j;
        float sx = sources[s*3+0], sy = sources[s*3+1], sz = sources[s*3+2];

        float dx = tpx - sx, dy = tpy - sy, dz = tpz - sz;
        float il = frsq(dx*dx + dy*dy + dz*dz);
        dx *= il; dy *= il; dz *= il;
        float ux = -dx, uy = -dy, uz = -dz;

        unsigned pm = masks[(unsigned)m * NS + (unsigned)s];
        pm = __builtin_amdgcn_readfirstlane(pm);
        unsigned cmask = pm & 0xFFFFu;
        unsigned bmask = (pm >> 16) & 0xFFu;

        bool hit = false;

        while (cmask) {
            int c = __builtin_ctz(cmask);
            cmask &= cmask - 1;
            float4 c0 = s_cyl[c][0];
            float4 c1 = s_cyl[c][1];
            float ocx = tpx - c0.x, ocy = tpy - c0.y, ocz = tpz - c0.z;
            float oa  = ocx*c1.x + ocy*c1.y + ocz*c1.z;
            float Cc  = ocx*ocx + ocy*ocy + ocz*ocz - oa*oa - c1.w;
            float ua  = ux*c1.x + uy*c1.y + uz*c1.z;
            float ocu = ux*ocx + uy*ocy + uz*ocz;
            float Bh  = fmaf(-oa, ua, ocu);
            float A   = fmaf(-ua, ua, 1.0f);
            float disc = fmaf(Bh, Bh, -(A*Cc));
            float sq   = fsqrt_(fmaxf(disc, 0.0f));
            float Ah   = A + 0.5f*FEPS;
            float q1   = -Bh - sq;
            float q2   = -Bh + sq;
            float oaA  = oa * Ah;
            float LA   = c0.w * Ah;
            float epsA = FEPS * Ah;
            float ax1A = fmaf(q1, ua, oaA);
            float ax2A = fmaf(q2, ua, oaA);
            bool dpos  = disc > 0.0f;
            hit = hit | (dpos & (q1 > epsA) & (ax1A >= 0.0f) & (ax1A <= LA))
                      | (dpos & (q2 > epsA) & (ax2A >= 0.0f) & (ax2A <= LA));
        }

        if (bmask) {
            float ivx = frcp((fabsf(ux) < FEPS) ? FEPS : ux);
            float ivy = frcp((fabsf(uy) < FEPS) ? FEPS : uy);
            float ivz = frcp((fabsf(uz) < FEPS) ? FEPS : uz);
            while (bmask) {
                int b = __builtin_ctz(bmask);
                bmask &= bmask - 1;
                float4 b1 = s_box[b][0];
                float4 b2 = s_box[b][1];
                float t0x = (b1.x - tpx) * ivx, t1x = (b2.x - tpx) * ivx;
                float t0y = (b1.y - tpy) * ivy, t1y = (b2.y - tpy) * ivy;
                float t0z = (b1.z - tpz) * ivz, t1z = (b2.z - tpz) * ivz;
                float tmin = fmaxf(fmaxf(fminf(t0x,t1x), fminf(t0y,t1y)), fminf(t0z,t1z));
                float tmax = fminf(fminf(fmaxf(t0x,t1x), fmaxf(t0y,t1y)), fmaxf(t0z,t1z));
                hit = hit | (tmax >= fmaxf(tmin, FEPS));
            }
        }

        float dn = dx*tnx + dy*tny + dz*tnz;
        float rx = fmaf(-2.0f*dn, tnx, dx);
        float ry = fmaf(-2.0f*dn, tny, dy);
        float rz = fmaf(-2.0f*dn, tnz, dz);
        float cosv  = fabsf(dn);
        float denom = rx*spnx + ry*spny + rz*spnz;
        float tt = num * frcp(denom + FEPS);
        float qx = fmaf(tt, rx, tpx);
        float qy = fmaf(tt, ry, tpy);
        float fx = (qx + FEXT) * PXSCALE;
        float fy = (qy + FEXT) * PXSCALE;
        float fxf = floorf(fx), fyf = floorf(fy);
        bool inb = (fxf >= 0.0f) & (fxf < (float)IW) & (fyf >= 0.0f) & (fyf < (float)IH)
                   & (!hit);
        if (inb) {
            int ix = (int)fxf, iy = (int)fyf;
            unsigned pix = (unsigned)(iy * IW + ix);
            unsigned q = (unsigned)(cosv * 16383.0f + 0.5f);
            if (q > 16383u) q = 16383u;
            rec[j]    = (pix << 14) | q;
            int tl    = ((iy >> 5) << 4) | (ix >> 5);
            tileid[j] = tl;
            rank[j]   = atomicAdd(&s_cnt[tl], 1u);
            vmask    |= (1u << j);
        }
    }
    __syncthreads();

    // Inclusive scan of s_cnt -> s_inc (Hillis-Steele, 256 entries).
    s_inc[t] = s_cnt[t];
    __syncthreads();
    for (int st = 1; st < NTILE; st <<= 1) {
        unsigned v = (t >= st) ? s_inc[t - st] : 0u;
        __syncthreads();
        s_inc[t] += v;
        __syncthreads();
    }
    unsigned total = s_inc[NTILE - 1];
    if (t == 0) s_base = total ? atomicAdd(galloc, total) : 0u;
    __syncthreads();

    // Stage records grouped by tile in LDS.
    #pragma unroll
    for (int j = 0; j < SPT; j++) {
        if (vmask & (1u << j)) {
            int tl = tileid[j];
            unsigned off = s_inc[tl] - s_cnt[tl];
            s_scratch[off + rank[j]] = rec[j];
        }
    }
    __syncthreads();

    // Coalesced copy to global arena.
    unsigned base = s_base;
    for (unsigned i = t; i < total; i += 256) arena[base + i] = s_scratch[i];

    // Emit one descriptor per non-empty tile (thread t owns tile t).
    unsigned c = s_cnt[t];
    if (c > 0) {
        unsigned off  = s_inc[t] - c;
        unsigned slot = atomicAdd(&desc_cnt[t], 1u);
        if (slot < MAXD) {
            desc[(size_t)t * MAXD + slot] = make_uint2(base + off, ((unsigned)t << 16) | c);
        } else {
            // statistically-never overflow: flush directly (device atomics)
            for (unsigned k = 0; k < c; k++) {
                unsigned r = s_scratch[off + k];
                atomicAdd(&img_direct[r >> 14], (float)(r & 16383u) * (1.0f/16383.0f));
            }
        }
    }
}

// ================= pass 2: per-tile LDS accumulation, atomic-free flush
__global__ __launch_bounds__(256) void tile_accum_kernel(
    const unsigned* __restrict__ arena, const uint2* __restrict__ desc,
    const unsigned* __restrict__ desc_cnt, float* __restrict__ gimg)
{
    __shared__ float tile[1024];
    const int t   = blockIdx.x;   // tile id
    const int g   = blockIdx.y;   // split group
    const int tid = threadIdx.x;

    for (int i = tid; i < 1024; i += 256) tile[i] = 0.0f;
    __syncthreads();

    unsigned nd = desc_cnt[t];
    if (nd > MAXD) nd = MAXD;
    for (unsigned d = g; d < nd; d += GSPLIT) {
        uint2 dd = desc[(size_t)t * MAXD + d];
        unsigned start = dd.x;
        unsigned cnt   = dd.y & 0xFFFFu;
        for (unsigned i = tid; i < cnt; i += 256) {
            unsigned rec = arena[start + i];
            unsigned pix = rec >> 14;
            float val = (float)(rec & 16383u) * (1.0f/16383.0f);
            unsigned ix = pix & 511u, iy = pix >> 9;
            unsigned lp = ((iy & 31u) << 5) | (ix & 31u);
            atomicAdd(&tile[lp], val);   // LDS atomic — per-CU, cheap
        }
    }
    __syncthreads();

    // tiles partition the image; (t,g) is unique -> plain stores, no atomics
    const unsigned ty = t >> 4, tx = t & 15;
    float* out = gimg + (size_t)g * NPIX;
    for (int i = tid; i < 1024; i += 256) {
        unsigned gy = ty * 32 + (i >> 5);
        unsigned gx = tx * 32 + (i & 31);
        out[gy * IW + gx] = tile[i];
    }
}

__global__ __launch_bounds__(256) void reduce_bin_kernel(
    const float* __restrict__ gimg, float* __restrict__ out)
{
    int i = blockIdx.x * 256 + threadIdx.x;
    float v = out[i];   // direct-flush atomics already landed in out
    #pragma unroll
    for (int g = 0; g < GSPLIT; g++) v += gimg[(size_t)g * NPIX + i];
    out[i] = v;
}

// ================= R7 fallback (ws too small): direct-atomic pipeline
__global__ __launch_bounds__(256) void render_kernel(
    const float* __restrict__ sources, const float* __restrict__ mpts,
    const float* __restrict__ mnrm,    const float* __restrict__ mpos,
    const float* __restrict__ mrot,
    const float* __restrict__ cp1g, const float* __restrict__ cp2g,
    const float* __restrict__ crad, const float* __restrict__ bp1g,
    const float* __restrict__ bp2g, const float* __restrict__ spp,
    const float* __restrict__ spn,  const unsigned* __restrict__ masks,
    float* __restrict__ imgs, int K)
{
    __shared__ float4 s_cyl[NCYL][2];
    __shared__ float4 s_box[NBOX][2];

    const int t  = threadIdx.x;
    const int n  = blockIdx.x * 256 + t;
    const int s0 = blockIdx.y * SPT;
    const int m  = blockIdx.z;

    const long idx = ((long)m * NP + n) * 3;
    float px = mpts[idx+0], py = mpts[idx+1], pz = mpts[idx+2];
    float nx = mnrm[idx+0], ny = mnrm[idx+1], nz = mnrm[idx+2];

    if (t < NCYL) {
        float p1x = cp1g[t*3+0], p1y = cp1g[t*3+1], p1z = cp1g[t*3+2];
        float axx = cp2g[t*3+0] - p1x;
        float axy = cp2g[t*3+1] - p1y;
        float axz = cp2g[t*3+2] - p1z;
        float L   = sqrtf(axx*axx + axy*axy + axz*axz);
        float inv = 1.0f / (L + FEPS);
        float r   = crad[t];
        s_cyl[t][0] = make_float4(p1x, p1y, p1z, L);
        s_cyl[t][1] = make_float4(axx*inv, axy*inv, axz*inv, r*r);
    } else if (t < NCYL + NBOX) {
        int b = t - NCYL;
        s_box[b][0] = make_float4(bp1g[b*3+0], bp1g[b*3+1], bp1g[b*3+2], 0.0f);
        s_box[b][1] = make_float4(bp2g[b*3+0], bp2g[b*3+1], bp2g[b*3+2], 0.0f);
    }
    __syncthreads();

    float R0 = mrot[m*9+0], R1 = mrot[m*9+1], R2 = mrot[m*9+2];
    float R3 = mrot[m*9+3], R4 = mrot[m*9+4], R5 = mrot[m*9+5];
    float R6 = mrot[m*9+6], R7 = mrot[m*9+7], R8 = mrot[m*9+8];
    float posx = mpos[m*3+0], posy = mpos[m*3+1], posz = mpos[m*3+2];
    float sppx = spp[0], sppy = spp[1], sppz = spp[2];
    float spnx = spn[0], spny = spn[1], spnz = spn[2];

    float tpx = R0*px + R1*py + R2*pz + posx;
    float tpy = R3*px + R4*py + R5*pz + posy;
    float tpz = R6*px + R7*py + R8*pz + posz;
    float tnx = R0*nx + R1*ny + R2*nz;
    float tny = R3*nx + R4*ny + R5*nz;
    float tnz = R6*nx + R7*ny + R8*nz;

    float num = (sppx-tpx)*spnx + (sppy-tpy)*spny + (sppz-tpz)*spnz;

    int linb = blockIdx.x + (int)gridDim.x * (blockIdx.y + (int)gridDim.y * blockIdx.z);
    float* __restrict__ img = imgs + (size_t)(linb % K) * NPIX;

    for (int j = 0; j < SPT; j++) {
        const int s = s0 + j;
        float sx = sources[s*3+0], sy = sources[s*3+1], sz = sources[s*3+2];

        float dx = tpx - sx, dy = tpy - sy, dz = tpz - sz;
        float il = frsq(dx*dx + dy*dy + dz*dz);
        dx *= il; dy *= il; dz *= il;
        float ux = -dx, uy = -dy, uz = -dz;

        unsigned pm = masks[(unsigned)m * NS + (unsigned)s];
        pm = __builtin_amdgcn_readfirstlane(pm);
        unsigned cmask = pm & 0xFFFFu;
        unsigned bmask = (pm >> 16) & 0xFFu;

        bool hit = false;

        while (cmask) {
            int c = __builtin_ctz(cmask);
            cmask &= cmask - 1;
            float4 c0 = s_cyl[c][0];
            float4 c1 = s_cyl[c][1];
            float ocx = tpx - c0.x, ocy = tpy - c0.y, ocz = tpz - c0.z;
            float oa  = ocx*c1.x + ocy*c1.y + ocz*c1.z;
            float Cc  = ocx*ocx + ocy*ocy + ocz*ocz - oa*oa - c1.w;
            float ua  = ux*c1.x + uy*c1.y + uz*c1.z;
            float ocu = ux*ocx + uy*ocy + uz*ocz;
            float Bh  = fmaf(-oa, ua, ocu);
            float A   = fmaf(-ua, ua, 1.0f);
            float disc = fmaf(Bh, Bh, -(A*Cc));
            float sq   = fsqrt_(fmaxf(disc, 0.0f));
            float Ah   = A + 0.5f*FEPS;
            float q1   = -Bh - sq;
            float q2   = -Bh + sq;
            float oaA  = oa * Ah;
            float LA   = c0.w * Ah;
            float epsA = FEPS * Ah;
            float ax1A = fmaf(q1, ua, oaA);
            float ax2A = fmaf(q2, ua, oaA);
            bool dpos  = disc > 0.0f;
            hit = hit | (dpos & (q1 > epsA) & (ax1A >= 0.0f) & (ax1A <= LA))
                      | (dpos & (q2 > epsA) & (ax2A >= 0.0f) & (ax2A <= LA));
        }

        if (bmask) {
            float ivx = frcp((fabsf(ux) < FEPS) ? FEPS : ux);
            float ivy = frcp((fabsf(uy) < FEPS) ? FEPS : uy);
            float ivz = frcp((fabsf(uz) < FEPS) ? FEPS : uz);
            while (bmask) {
                int b = __builtin_ctz(bmask);
                bmask &= bmask - 1;
                float4 b1 = s_box[b][0];
                float4 b2 = s_box[b][1];
                float t0x = (b1.x - tpx) * ivx, t1x = (b2.x - tpx) * ivx;
                float t0y = (b1.y - tpy) * ivy, t1y = (b2.y - tpy) * ivy;
                float t0z = (b1.z - tpz) * ivz, t1z = (b2.z - tpz) * ivz;
                float tmin = fmaxf(fmaxf(fminf(t0x,t1x), fminf(t0y,t1y)), fminf(t0z,t1z));
                float tmax = fminf(fminf(fmaxf(t0x,t1x), fmaxf(t0y,t1y)), fmaxf(t0z,t1z));
                hit = hit | (tmax >= fmaxf(tmin, FEPS));
            }
        }

        {
            float dn = dx*tnx + dy*tny + dz*tnz;
            float rx = fmaf(-2.0f*dn, tnx, dx);
            float ry = fmaf(-2.0f*dn, tny, dy);
            float rz = fmaf(-2.0f*dn, tnz, dz);
            float cosv  = fabsf(dn);
            float denom = rx*spnx + ry*spny + rz*spnz;
            float tt = num * frcp(denom + FEPS);
            float qx = fmaf(tt, rx, tpx);
            float qy = fmaf(tt, ry, tpy);
            float fx = (qx + FEXT) * PXSCALE;
            float fy = (qy + FEXT) * PXSCALE;
            float fxf = floorf(fx), fyf = floorf(fy);
            bool inb = (fxf >= 0.0f) & (fxf < (float)IW) & (fyf >= 0.0f) & (fyf < (float)IH)
                       & (!hit);
            if (inb) atomicAdd(&img[(int)fyf * IW + (int)fxf], cosv);
        }
    }
}

__global__ __launch_bounds__(256) void reduce_kernel(
    const float* __restrict__ imgs, int K, float* __restrict__ out)
{
    int i = blockIdx.x * 256 + threadIdx.x;
    float v = 0.0f;
    for (int k = 0; k < K; k++) v += imgs[(size_t)k * NPIX + i];
    out[i] = v;
}

extern "C" void kernel_launch(void* const* d_in, const int* in_sizes, int n_in,
                              void* d_out, int out_size, void* d_ws, size_t ws_size,
                              hipStream_t stream) {
    const float* sources = (const float*)d_in[0];
    const float* mpts    = (const float*)d_in[1];
    const float* mnrm    = (const float*)d_in[2];
    const float* mpos    = (const float*)d_in[3];
    const float* mrot    = (const float*)d_in[4];
    const float* cp1     = (const float*)d_in[5];
    const float* cp2     = (const float*)d_in[6];
    const float* crad    = (const float*)d_in[7];
    const float* bp1     = (const float*)d_in[8];
    const float* bp2     = (const float*)d_in[9];
    const float* spp     = (const float*)d_in[10];
    const float* spn     = (const float*)d_in[11];

    const size_t ARENA_BYTES = (size_t)NM * NS * NP * 4u;            // 64 MiB
    const size_t DESC_BYTES  = (size_t)NTILE * MAXD * 8u;            //  8 MiB
    const size_t GIMG_BYTES  = (size_t)GSPLIT * NPIX * 4u;           //  8 MiB
    const size_t CNT_BYTES   = 4096;                                 // galloc + desc_cnt
    const size_t BND_BYTES   = 1024;
    const size_t MSK_BYTES   = (size_t)NM * NS * 4u;                 // 32 KiB
    const size_t NEED = ARENA_BYTES + DESC_BYTES + GIMG_BYTES + CNT_BYTES
                      + BND_BYTES + MSK_BYTES;

    if (ws_size >= NEED) {
        // ---------- binning pipeline ----------
        char* p = (char*)d_ws;
        unsigned* arena    = (unsigned*)p;                  p += ARENA_BYTES;
        uint2*    desc     = (uint2*)p;                     p += DESC_BYTES;
        float*    gimg     = (float*)p;                     p += GIMG_BYTES;
        unsigned* galloc   = (unsigned*)p;                  // [0] = alloc, [256..] desc_cnt
        unsigned* desc_cnt = galloc + 256;                  p += CNT_BYTES;
        float4*   bounds   = (float4*)p;                    p += BND_BYTES;
        unsigned* masks    = (unsigned*)p;

        hipMemsetAsync(galloc, 0, CNT_BYTES, stream);
        hipMemsetAsync(d_out, 0, (size_t)NPIX * sizeof(float), stream);  // direct-flush target

        mirror_bounds_kernel<<<NM, 256, 0, stream>>>(mpts, mpos, mrot, bounds);
        mask_kernel<<<(NM * NS + 255) / 256, 256, 0, stream>>>(
            sources, cp1, cp2, crad, bp1, bp2, bounds, masks);

        dim3 grid(NP / 256, NS / SPT, NM);   // (8,16,64) = 8192 blocks
        render_bin_kernel<<<grid, 256, 0, stream>>>(
            sources, mpts, mnrm, mpos, mrot, cp1, cp2, crad, bp1, bp2, spp, spn,
            masks, arena, desc, desc_cnt, galloc, (float*)d_out);

        dim3 grid2(NTILE, GSPLIT);           // 256 tiles x 8 splits
        tile_accum_kernel<<<grid2, 256, 0, stream>>>(arena, desc, desc_cnt, gimg);

        reduce_bin_kernel<<<NPIX / 256, 256, 0, stream>>>(gimg, (float*)d_out);
    } else {
        // ---------- R7 fallback: direct atomics with K privatized images ----------
        const size_t IMG_BYTES = (size_t)NPIX * sizeof(float);
        const size_t AUX_BYTES = 1024 + (size_t)NM * NS * sizeof(unsigned);
        int K = 0;
        for (int k = 8; k >= 1; k >>= 1) {
            if ((size_t)k * IMG_BYTES + AUX_BYTES <= ws_size) { K = k; break; }
        }
        float* imgs;
        char*  aux;
        if (K >= 1) {
            imgs = (float*)d_ws;
            aux  = (char*)d_ws + (size_t)K * IMG_BYTES;
            hipMemsetAsync(imgs, 0, (size_t)K * IMG_BYTES, stream);
        } else {
            K    = 1;
            imgs = (float*)d_out;
            aux  = (char*)d_ws;
            hipMemsetAsync(imgs, 0, IMG_BYTES, stream);
        }
        float4*   bounds = (float4*)aux;
        unsigned* masks  = (unsigned*)(aux + 1024);

        mirror_bounds_kernel<<<NM, 256, 0, stream>>>(mpts, mpos, mrot, bounds);
        mask_kernel<<<(NM * NS + 255) / 256, 256, 0, stream>>>(
            sources, cp1, cp2, crad, bp1, bp2, bounds, masks);

        dim3 grid(NP / 256, NS / SPT, NM);
        render_kernel<<<grid, 256, 0, stream>>>(sources, mpts, mnrm, mpos, mrot,
                                                cp1, cp2, crad, bp1, bp2, spp, spn,
                                                masks, imgs, K);
        if (imgs != (float*)d_out) {
            reduce_kernel<<<NPIX / 256, 256, 0, stream>>>(imgs, K, (float*)d_out);
        }
    }
}

// Round 9
// 583.746 us; speedup vs baseline: 1.7894x; 1.0085x over previous
//
#include <hip/hip_runtime.h>

// S,P,M=(128,2048,64), NC,NB=(16,8), H,W=512, EXTENT=12, EPS=1e-9
#define NS   128
#define NP   2048
#define NM   64
#define NCYL 16
#define NBOX 8
#define IH   512
#define IW   512
#define NPIX (IH*IW)
#define FEXT 12.0f
#define FEPS 1e-9f
#define PXSCALE ((float)IW / (2.0f * FEXT))
#define PRUNE_MARGIN 0.05f
#define SPT  8      // sources per thread
#define NTILE 256   // 16x16 grid of 32x32-pixel tiles
#define GSPLIT 8    // pass-2 blocks per tile

__device__ __forceinline__ float frcp(float x)   { return __builtin_amdgcn_rcpf(x); }
__device__ __forceinline__ float frsq(float x)   { return __builtin_amdgcn_rsqf(x); }
__device__ __forceinline__ float fsqrt_(float x) { return __builtin_amdgcn_sqrtf(x); }
__device__ __forceinline__ float clamp01(float x){ return fminf(fmaxf(x, 0.0f), 1.0f); }

// ---------------- Pre-pass A: per-mirror bounding sphere of transformed points
__global__ __launch_bounds__(256) void mirror_bounds_kernel(
    const float* __restrict__ mpts, const float* __restrict__ mpos,
    const float* __restrict__ mrot, float4* __restrict__ bounds)
{
    const int m = blockIdx.x;
    const int t = threadIdx.x;
    float R0 = mrot[m*9+0], R1 = mrot[m*9+1], R2 = mrot[m*9+2];
    float R3 = mrot[m*9+3], R4 = mrot[m*9+4], R5 = mrot[m*9+5];
    float R6 = mrot[m*9+6], R7 = mrot[m*9+7], R8 = mrot[m*9+8];
    float posx = mpos[m*3+0], posy = mpos[m*3+1], posz = mpos[m*3+2];

    float mnx = 1e30f, mny = 1e30f, mnz = 1e30f;
    float mxx = -1e30f, mxy = -1e30f, mxz = -1e30f;
    for (int i = t; i < NP; i += 256) {
        long id = ((long)m * NP + i) * 3;
        float px = mpts[id+0], py = mpts[id+1], pz = mpts[id+2];
        float tx = R0*px + R1*py + R2*pz + posx;
        float ty = R3*px + R4*py + R5*pz + posy;
        float tz = R6*px + R7*py + R8*pz + posz;
        mnx = fminf(mnx, tx); mny = fminf(mny, ty); mnz = fminf(mnz, tz);
        mxx = fmaxf(mxx, tx); mxy = fmaxf(mxy, ty); mxz = fmaxf(mxz, tz);
    }
    __shared__ float red[6][256];
    red[0][t] = mnx; red[1][t] = mny; red[2][t] = mnz;
    red[3][t] = mxx; red[4][t] = mxy; red[5][t] = mxz;
    __syncthreads();
    for (int off = 128; off > 0; off >>= 1) {
        if (t < off) {
            red[0][t] = fminf(red[0][t], red[0][t+off]);
            red[1][t] = fminf(red[1][t], red[1][t+off]);
            red[2][t] = fminf(red[2][t], red[2][t+off]);
            red[3][t] = fmaxf(red[3][t], red[3][t+off]);
            red[4][t] = fmaxf(red[4][t], red[4][t+off]);
            red[5][t] = fmaxf(red[5][t], red[5][t+off]);
        }
        __syncthreads();
    }
    if (t == 0) {
        float cx = 0.5f*(red[0][0]+red[3][0]);
        float cy = 0.5f*(red[1][0]+red[4][0]);
        float cz = 0.5f*(red[2][0]+red[5][0]);
        float hx = 0.5f*(red[3][0]-red[0][0]);
        float hy = 0.5f*(red[4][0]-red[1][0]);
        float hz = 0.5f*(red[5][0]-red[2][0]);
        float r  = sqrtf(hx*hx + hy*hy + hz*hz);
        bounds[m] = make_float4(cx, cy, cz, r);
    }
}

// ---------------- Pre-pass B: per-(mirror,source) occluder mask (conservative)
__global__ __launch_bounds__(256) void mask_kernel(
    const float* __restrict__ sources,
    const float* __restrict__ cp1g, const float* __restrict__ cp2g,
    const float* __restrict__ crad,
    const float* __restrict__ bp1g, const float* __restrict__ bp2g,
    const float4* __restrict__ bounds, unsigned* __restrict__ masks)
{
    int pair = blockIdx.x * 256 + threadIdx.x;
    if (pair >= NM * NS) return;
    int m = pair / NS;
    int s = pair - m * NS;

    float4 bd = bounds[m];
    float cx = bd.x, cy = bd.y, cz = bd.z;
    float rm = bd.w + PRUNE_MARGIN;
    float sx = sources[s*3+0], sy = sources[s*3+1], sz = sources[s*3+2];

    float d1x = sx - cx, d1y = sy - cy, d1z = sz - cz;
    float a = d1x*d1x + d1y*d1y + d1z*d1z;

    unsigned mask = 0;

    for (int c = 0; c < NCYL; c++) {
        float p2x = cp1g[c*3+0], p2y = cp1g[c*3+1], p2z = cp1g[c*3+2];
        float d2x = cp2g[c*3+0] - p2x, d2y = cp2g[c*3+1] - p2y, d2z = cp2g[c*3+2] - p2z;
        float rx = cx - p2x, ry = cy - p2y, rz = cz - p2z;
        float e = d2x*d2x + d2y*d2y + d2z*d2z;
        float f = d2x*rx + d2y*ry + d2z*rz;
        float cc = d1x*rx + d1y*ry + d1z*rz;
        float b = d1x*d2x + d1y*d2y + d1z*d2z;
        float denom = a*e - b*b;
        float sN = (denom > 1e-6f) ? clamp01((b*f - cc*e) / denom) : 0.0f;
        float tN = (b*sN + f) / e;
        if (tN < 0.0f)      { tN = 0.0f; sN = clamp01(-cc / a); }
        else if (tN > 1.0f) { tN = 1.0f; sN = clamp01((b - cc) / a); }
        float gx = (cx + d1x*sN) - (p2x + d2x*tN);
        float gy = (cy + d1y*sN) - (p2y + d2y*tN);
        float gz = (cz + d1z*sN) - (p2z + d2z*tN);
        float dist2 = gx*gx + gy*gy + gz*gz;
        float thr = crad[c] + rm;
        if (dist2 <= thr*thr) mask |= (1u << c);
    }

    float ivx = 1.0f / ((fabsf(d1x) < FEPS) ? FEPS : d1x);
    float ivy = 1.0f / ((fabsf(d1y) < FEPS) ? FEPS : d1y);
    float ivz = 1.0f / ((fabsf(d1z) < FEPS) ? FEPS : d1z);
    for (int b = 0; b < NBOX; b++) {
        float lx = bp1g[b*3+0] - rm, ly = bp1g[b*3+1] - rm, lz = bp1g[b*3+2] - rm;
        float hx = bp2g[b*3+0] + rm, hy = bp2g[b*3+1] + rm, hz = bp2g[b*3+2] + rm;
        float t0x = (lx - cx) * ivx, t1x = (hx - cx) * ivx;
        float t0y = (ly - cy) * ivy, t1y = (hy - cy) * ivy;
        float t0z = (lz - cz) * ivz, t1z = (hz - cz) * ivz;
        float tmin = fmaxf(fmaxf(fminf(t0x,t1x), fminf(t0y,t1y)), fminf(t0z,t1z));
        float tmax = fminf(fminf(fmaxf(t0x,t1x), fmaxf(t0y,t1y)), fmaxf(t0z,t1z));
        if (fmaxf(tmin, 0.0f) <= fminf(tmax, 1.0f)) mask |= (1u << (16 + b));
    }

    masks[pair] = mask;
}

// ================= BINNING PIPELINE (pass 1): rays -> tile-grouped records
__global__ __launch_bounds__(256) void render_bin_kernel(
    const float* __restrict__ sources, const float* __restrict__ mpts,
    const float* __restrict__ mnrm,    const float* __restrict__ mpos,
    const float* __restrict__ mrot,
    const float* __restrict__ cp1g, const float* __restrict__ cp2g,
    const float* __restrict__ crad, const float* __restrict__ bp1g,
    const float* __restrict__ bp2g, const float* __restrict__ spp,
    const float* __restrict__ spn,  const unsigned* __restrict__ masks,
    unsigned* __restrict__ arena, uint2* __restrict__ desc,
    unsigned* __restrict__ desc_cnt, unsigned* __restrict__ galloc,
    float* __restrict__ img_direct, int maxd)
{
    __shared__ float4 s_cyl[NCYL][2];
    __shared__ float4 s_box[NBOX][2];
    __shared__ unsigned s_cnt[NTILE];
    __shared__ unsigned s_inc[NTILE];
    __shared__ unsigned s_scratch[256 * SPT];
    __shared__ unsigned s_base;
    __shared__ unsigned s_of[32][2];
    __shared__ unsigned s_ofn;

    const int t  = threadIdx.x;
    const int n  = blockIdx.x * 256 + t;
    const int s0 = blockIdx.y * SPT;
    const int m  = blockIdx.z;

    const long idx = ((long)m * NP + n) * 3;
    float px = mpts[idx+0], py = mpts[idx+1], pz = mpts[idx+2];
    float nx = mnrm[idx+0], ny = mnrm[idx+1], nz = mnrm[idx+2];

    s_cnt[t] = 0;   // 256 threads == NTILE
    if (t == 0) s_ofn = 0;
    if (t < NCYL) {
        float p1x = cp1g[t*3+0], p1y = cp1g[t*3+1], p1z = cp1g[t*3+2];
        float axx = cp2g[t*3+0] - p1x;
        float axy = cp2g[t*3+1] - p1y;
        float axz = cp2g[t*3+2] - p1z;
        float L   = sqrtf(axx*axx + axy*axy + axz*axz);
        float inv = 1.0f / (L + FEPS);
        float r   = crad[t];
        s_cyl[t][0] = make_float4(p1x, p1y, p1z, L);
        s_cyl[t][1] = make_float4(axx*inv, axy*inv, axz*inv, r*r);
    } else if (t < NCYL + NBOX) {
        int b = t - NCYL;
        s_box[b][0] = make_float4(bp1g[b*3+0], bp1g[b*3+1], bp1g[b*3+2], 0.0f);
        s_box[b][1] = make_float4(bp2g[b*3+0], bp2g[b*3+1], bp2g[b*3+2], 0.0f);
    }
    __syncthreads();

    float R0 = mrot[m*9+0], R1 = mrot[m*9+1], R2 = mrot[m*9+2];
    float R3 = mrot[m*9+3], R4 = mrot[m*9+4], R5 = mrot[m*9+5];
    float R6 = mrot[m*9+6], R7 = mrot[m*9+7], R8 = mrot[m*9+8];
    float posx = mpos[m*3+0], posy = mpos[m*3+1], posz = mpos[m*3+2];
    float sppx = spp[0], sppy = spp[1], sppz = spp[2];
    float spnx = spn[0], spny = spn[1], spnz = spn[2];

    float tpx = R0*px + R1*py + R2*pz + posx;
    float tpy = R3*px + R4*py + R5*pz + posy;
    float tpz = R6*px + R7*py + R8*pz + posz;
    float tnx = R0*nx + R1*ny + R2*nz;
    float tny = R3*nx + R4*ny + R5*nz;
    float tnz = R6*nx + R7*ny + R8*nz;

    float num = (sppx-tpx)*spnx + (sppy-tpy)*spny + (sppz-tpz)*spnz;

    unsigned rec[SPT];
    unsigned rank[SPT];
    int      tileid[SPT];
    unsigned vmask = 0;

    #pragma unroll
    for (int j = 0; j < SPT; j++) {
        const int s = s0 + j;
        float sx = sources[s*3+0], sy = sources[s*3+1], sz = sources[s*3+2];

        float dx = tpx - sx, dy = tpy - sy, dz = tpz - sz;
        float il = frsq(dx*dx + dy*dy + dz*dz);
        dx *= il; dy *= il; dz *= il;
        float ux = -dx, uy = -dy, uz = -dz;

        unsigned pm = masks[(unsigned)m * NS + (unsigned)s];
        pm = __builtin_amdgcn_readfirstlane(pm);
        unsigned cmask = pm & 0xFFFFu;
        unsigned bmask = (pm >> 16) & 0xFFu;

        bool hit = false;

        while (cmask) {
            int c = __builtin_ctz(cmask);
            cmask &= cmask - 1;
            float4 c0 = s_cyl[c][0];
            float4 c1 = s_cyl[c][1];
            float ocx = tpx - c0.x, ocy = tpy - c0.y, ocz = tpz - c0.z;
            float oa  = ocx*c1.x + ocy*c1.y + ocz*c1.z;
            float Cc  = ocx*ocx + ocy*ocy + ocz*ocz - oa*oa - c1.w;
            float ua  = ux*c1.x + uy*c1.y + uz*c1.z;
            float ocu = ux*ocx + uy*ocy + uz*ocz;
            float Bh  = fmaf(-oa, ua, ocu);
            float A   = fmaf(-ua, ua, 1.0f);
            float disc = fmaf(Bh, Bh, -(A*Cc));
            float sq   = fsqrt_(fmaxf(disc, 0.0f));
            float Ah   = A + 0.5f*FEPS;
            float q1   = -Bh - sq;
            float q2   = -Bh + sq;
            float oaA  = oa * Ah;
            float LA   = c0.w * Ah;
            float epsA = FEPS * Ah;
            float ax1A = fmaf(q1, ua, oaA);
            float ax2A = fmaf(q2, ua, oaA);
            bool dpos  = disc > 0.0f;
            hit = hit | (dpos & (q1 > epsA) & (ax1A >= 0.0f) & (ax1A <= LA))
                      | (dpos & (q2 > epsA) & (ax2A >= 0.0f) & (ax2A <= LA));
        }

        if (bmask) {
            float ivx = frcp((fabsf(ux) < FEPS) ? FEPS : ux);
            float ivy = frcp((fabsf(uy) < FEPS) ? FEPS : uy);
            float ivz = frcp((fabsf(uz) < FEPS) ? FEPS : uz);
            while (bmask) {
                int b = __builtin_ctz(bmask);
                bmask &= bmask - 1;
                float4 b1 = s_box[b][0];
                float4 b2 = s_box[b][1];
                float t0x = (b1.x - tpx) * ivx, t1x = (b2.x - tpx) * ivx;
                float t0y = (b1.y - tpy) * ivy, t1y = (b2.y - tpy) * ivy;
                float t0z = (b1.z - tpz) * ivz, t1z = (b2.z - tpz) * ivz;
                float tmin = fmaxf(fmaxf(fminf(t0x,t1x), fminf(t0y,t1y)), fminf(t0z,t1z));
                float tmax = fminf(fminf(fmaxf(t0x,t1x), fmaxf(t0y,t1y)), fmaxf(t0z,t1z));
                hit = hit | (tmax >= fmaxf(tmin, FEPS));
            }
        }

        float dn = dx*tnx + dy*tny + dz*tnz;
        float rx = fmaf(-2.0f*dn, tnx, dx);
        float ry = fmaf(-2.0f*dn, tny, dy);
        float rz = fmaf(-2.0f*dn, tnz, dz);
        float cosv  = fabsf(dn);
        float denom = rx*spnx + ry*spny + rz*spnz;
        float tt = num * frcp(denom + FEPS);
        float qx = fmaf(tt, rx, tpx);
        float qy = fmaf(tt, ry, tpy);
        float fx = (qx + FEXT) * PXSCALE;
        float fy = (qy + FEXT) * PXSCALE;
        float fxf = floorf(fx), fyf = floorf(fy);
        bool inb = (fxf >= 0.0f) & (fxf < (float)IW) & (fyf >= 0.0f) & (fyf < (float)IH)
                   & (!hit);
        if (inb) {
            int ix = (int)fxf, iy = (int)fyf;
            unsigned pix = (unsigned)(iy * IW + ix);
            unsigned q = (unsigned)(cosv * 16383.0f + 0.5f);
            if (q > 16383u) q = 16383u;
            rec[j]    = (pix << 14) | q;
            int tl    = ((iy >> 5) << 4) | (ix >> 5);
            tileid[j] = tl;
            rank[j]   = atomicAdd(&s_cnt[tl], 1u);
            vmask    |= (1u << j);
        }
    }
    __syncthreads();

    // Inclusive scan of s_cnt -> s_inc (Hillis-Steele, 256 entries).
    s_inc[t] = s_cnt[t];
    __syncthreads();
    for (int st = 1; st < NTILE; st <<= 1) {
        unsigned v = (t >= st) ? s_inc[t - st] : 0u;
        __syncthreads();
        s_inc[t] += v;
        __syncthreads();
    }
    unsigned total = s_inc[NTILE - 1];
    if (t == 0) s_base = total ? atomicAdd(galloc, total) : 0u;
    __syncthreads();

    // Stage records grouped by tile in LDS.
    #pragma unroll
    for (int j = 0; j < SPT; j++) {
        if (vmask & (1u << j)) {
            int tl = tileid[j];
            unsigned off = s_inc[tl] - s_cnt[tl];
            s_scratch[off + rank[j]] = rec[j];
        }
    }
    __syncthreads();

    // Coalesced copy to global arena.
    unsigned base = s_base;
    for (unsigned i = t; i < total; i += 256) arena[base + i] = s_scratch[i];

    // Emit one descriptor per non-empty tile (thread t owns tile t).
    unsigned c = s_cnt[t];
    if (c > 0) {
        unsigned off  = s_inc[t] - c;
        unsigned slot = atomicAdd(&desc_cnt[t], 1u);
        if (slot < (unsigned)maxd) {
            desc[(size_t)t * maxd + slot] = make_uint2(base + off, ((unsigned)t << 16) | c);
        } else {
            unsigned k = atomicAdd(&s_ofn, 1u);
            if (k < 32u) { s_of[k][0] = off; s_of[k][1] = c; }
            else {
                // beyond 32 overflows in one block: serial flush (statistically never)
                for (unsigned q = 0; q < c; q++) {
                    unsigned r = s_scratch[off + q];
                    atomicAdd(&img_direct[r >> 14], (float)(r & 16383u) * (1.0f/16383.0f));
                }
            }
        }
    }
    __syncthreads();

    // Cooperative (256-wide) flush of overflowed segments.
    unsigned nof = s_ofn < 32u ? s_ofn : 32u;
    for (unsigned k = 0; k < nof; k++) {
        unsigned off = s_of[k][0], cc = s_of[k][1];
        for (unsigned i = t; i < cc; i += 256) {
            unsigned r = s_scratch[off + i];
            atomicAdd(&img_direct[r >> 14], (float)(r & 16383u) * (1.0f/16383.0f));
        }
    }
}

// ================= pass 2: per-tile LDS accumulation, wave-parallel descriptors
__global__ __launch_bounds__(256) void tile_accum_kernel(
    const unsigned* __restrict__ arena, const uint2* __restrict__ desc,
    const unsigned* __restrict__ desc_cnt, int maxd, float* __restrict__ gimg)
{
    __shared__ float tile[1024];
    const int t    = blockIdx.x;   // tile id
    const int g    = blockIdx.y;   // split group
    const int tid  = threadIdx.x;
    const int wid  = tid >> 6;     // wave id (0..3)
    const int lane = tid & 63;

    for (int i = tid; i < 1024; i += 256) tile[i] = 0.0f;
    __syncthreads();

    unsigned nd = desc_cnt[t];
    if (nd > (unsigned)maxd) nd = (unsigned)maxd;

    const uint2* __restrict__ dbase = desc + (size_t)t * maxd;
    const unsigned stride = GSPLIT * 4;       // 8 splits x 4 waves = 32 streams/tile

    // Two-deep software-pipelined descriptor walk, one stream per wave.
    unsigned d = (unsigned)(g * 4 + wid);
    uint2 dd = (d < nd) ? dbase[d] : make_uint2(0u, 0u);
    while (d < nd) {
        unsigned d2 = d + stride;
        uint2 dd2 = (d2 < nd) ? dbase[d2] : make_uint2(0u, 0u);   // prefetch next
        unsigned start = dd.x;
        unsigned cnt   = dd.y & 0xFFFFu;
        for (unsigned i = lane; i < cnt; i += 64) {
            unsigned rec = arena[start + i];
            unsigned pix = rec >> 14;
            float val = (float)(rec & 16383u) * (1.0f/16383.0f);
            unsigned ix = pix & 511u, iy = pix >> 9;
            unsigned lp = ((iy & 31u) << 5) | (ix & 31u);
            atomicAdd(&tile[lp], val);   // LDS atomic — per-CU
        }
        dd = dd2; d = d2;
    }
    __syncthreads();

    // tiles partition the image; (t,g) unique -> plain stores, no atomics
    const unsigned ty = t >> 4, tx = t & 15;
    float* out = gimg + (size_t)g * NPIX;
    for (int i = tid; i < 1024; i += 256) {
        unsigned gy = ty * 32 + (i >> 5);
        unsigned gx = tx * 32 + (i & 31);
        out[gy * IW + gx] = tile[i];
    }
}

__global__ __launch_bounds__(256) void reduce_bin_kernel(
    const float* __restrict__ gimg, float* __restrict__ out)
{
    int i = blockIdx.x * 256 + threadIdx.x;
    float v = out[i];   // direct-flush atomics already landed in out
    #pragma unroll
    for (int g = 0; g < GSPLIT; g++) v += gimg[(size_t)g * NPIX + i];
    out[i] = v;
}

// ================= R7 fallback (ws too small): direct-atomic pipeline
__global__ __launch_bounds__(256) void render_kernel(
    const float* __restrict__ sources, const float* __restrict__ mpts,
    const float* __restrict__ mnrm,    const float* __restrict__ mpos,
    const float* __restrict__ mrot,
    const float* __restrict__ cp1g, const float* __restrict__ cp2g,
    const float* __restrict__ crad, const float* __restrict__ bp1g,
    const float* __restrict__ bp2g, const float* __restrict__ spp,
    const float* __restrict__ spn,  const unsigned* __restrict__ masks,
    float* __restrict__ imgs, int K)
{
    __shared__ float4 s_cyl[NCYL][2];
    __shared__ float4 s_box[NBOX][2];

    const int t  = threadIdx.x;
    const int n  = blockIdx.x * 256 + t;
    const int s0 = blockIdx.y * SPT;
    const int m  = blockIdx.z;

    const long idx = ((long)m * NP + n) * 3;
    float px = mpts[idx+0], py = mpts[idx+1], pz = mpts[idx+2];
    float nx = mnrm[idx+0], ny = mnrm[idx+1], nz = mnrm[idx+2];

    if (t < NCYL) {
        float p1x = cp1g[t*3+0], p1y = cp1g[t*3+1], p1z = cp1g[t*3+2];
        float axx = cp2g[t*3+0] - p1x;
        float axy = cp2g[t*3+1] - p1y;
        float axz = cp2g[t*3+2] - p1z;
        float L   = sqrtf(axx*axx + axy*axy + axz*axz);
        float inv = 1.0f / (L + FEPS);
        float r   = crad[t];
        s_cyl[t][0] = make_float4(p1x, p1y, p1z, L);
        s_cyl[t][1] = make_float4(axx*inv, axy*inv, axz*inv, r*r);
    } else if (t < NCYL + NBOX) {
        int b = t - NCYL;
        s_box[b][0] = make_float4(bp1g[b*3+0], bp1g[b*3+1], bp1g[b*3+2], 0.0f);
        s_box[b][1] = make_float4(bp2g[b*3+0], bp2g[b*3+1], bp2g[b*3+2], 0.0f);
    }
    __syncthreads();

    float R0 = mrot[m*9+0], R1 = mrot[m*9+1], R2 = mrot[m*9+2];
    float R3 = mrot[m*9+3], R4 = mrot[m*9+4], R5 = mrot[m*9+5];
    float R6 = mrot[m*9+6], R7 = mrot[m*9+7], R8 = mrot[m*9+8];
    float posx = mpos[m*3+0], posy = mpos[m*3+1], posz = mpos[m*3+2];
    float sppx = spp[0], sppy = spp[1], sppz = spp[2];
    float spnx = spn[0], spny = spn[1], spnz = spn[2];

    float tpx = R0*px + R1*py + R2*pz + posx;
    float tpy = R3*px + R4*py + R5*pz + posy;
    float tpz = R6*px + R7*py + R8*pz + posz;
    float tnx = R0*nx + R1*ny + R2*nz;
    float tny = R3*nx + R4*ny + R5*nz;
    float tnz = R6*nx + R7*ny + R8*nz;

    float num = (sppx-tpx)*spnx + (sppy-tpy)*spny + (sppz-tpz)*spnz;

    int linb = blockIdx.x + (int)gridDim.x * (blockIdx.y + (int)gridDim.y * blockIdx.z);
    float* __restrict__ img = imgs + (size_t)(linb % K) * NPIX;

    for (int j = 0; j < SPT; j++) {
        const int s = s0 + j;
        float sx = sources[s*3+0], sy = sources[s*3+1], sz = sources[s*3+2];

        float dx = tpx - sx, dy = tpy - sy, dz = tpz - sz;
        float il = frsq(dx*dx + dy*dy + dz*dz);
        dx *= il; dy *= il; dz *= il;
        float ux = -dx, uy = -dy, uz = -dz;

        unsigned pm = masks[(unsigned)m * NS + (unsigned)s];
        pm = __builtin_amdgcn_readfirstlane(pm);
        unsigned cmask = pm & 0xFFFFu;
        unsigned bmask = (pm >> 16) & 0xFFu;

        bool hit = false;

        while (cmask) {
            int c = __builtin_ctz(cmask);
            cmask &= cmask - 1;
            float4 c0 = s_cyl[c][0];
            float4 c1 = s_cyl[c][1];
            float ocx = tpx - c0.x, ocy = tpy - c0.y, ocz = tpz - c0.z;
            float oa  = ocx*c1.x + ocy*c1.y + ocz*c1.z;
            float Cc  = ocx*ocx + ocy*ocy + ocz*ocz - oa*oa - c1.w;
            float ua  = ux*c1.x + uy*c1.y + uz*c1.z;
            float ocu = ux*ocx + uy*ocy + uz*ocz;
            float Bh  = fmaf(-oa, ua, ocu);
            float A   = fmaf(-ua, ua, 1.0f);
            float disc = fmaf(Bh, Bh, -(A*Cc));
            float sq   = fsqrt_(fmaxf(disc, 0.0f));
            float Ah   = A + 0.5f*FEPS;
            float q1   = -Bh - sq;
            float q2   = -Bh + sq;
            float oaA  = oa * Ah;
            float LA   = c0.w * Ah;
            float epsA = FEPS * Ah;
            float ax1A = fmaf(q1, ua, oaA);
            float ax2A = fmaf(q2, ua, oaA);
            bool dpos  = disc > 0.0f;
            hit = hit | (dpos & (q1 > epsA) & (ax1A >= 0.0f) & (ax1A <= LA))
                      | (dpos & (q2 > epsA) & (ax2A >= 0.0f) & (ax2A <= LA));
        }

        if (bmask) {
            float ivx = frcp((fabsf(ux) < FEPS) ? FEPS : ux);
            float ivy = frcp((fabsf(uy) < FEPS) ? FEPS : uy);
            float ivz = frcp((fabsf(uz) < FEPS) ? FEPS : uz);
            while (bmask) {
                int b = __builtin_ctz(bmask);
                bmask &= bmask - 1;
                float4 b1 = s_box[b][0];
                float4 b2 = s_box[b][1];
                float t0x = (b1.x - tpx) * ivx, t1x = (b2.x - tpx) * ivx;
                float t0y = (b1.y - tpy) * ivy, t1y = (b2.y - tpy) * ivy;
                float t0z = (b1.z - tpz) * ivz, t1z = (b2.z - tpz) * ivz;
                float tmin = fmaxf(fmaxf(fminf(t0x,t1x), fminf(t0y,t1y)), fminf(t0z,t1z));
                float tmax = fminf(fminf(fmaxf(t0x,t1x), fmaxf(t0y,t1y)), fmaxf(t0z,t1z));
                hit = hit | (tmax >= fmaxf(tmin, FEPS));
            }
        }

        {
            float dn = dx*tnx + dy*tny + dz*tnz;
            float rx = fmaf(-2.0f*dn, tnx, dx);
            float ry = fmaf(-2.0f*dn, tny, dy);
            float rz = fmaf(-2.0f*dn, tnz, dz);
            float cosv  = fabsf(dn);
            float denom = rx*spnx + ry*spny + rz*spnz;
            float tt = num * frcp(denom + FEPS);
            float qx = fmaf(tt, rx, tpx);
            float qy = fmaf(tt, ry, tpy);
            float fx = (qx + FEXT) * PXSCALE;
            float fy = (qy + FEXT) * PXSCALE;
            float fxf = floorf(fx), fyf = floorf(fy);
            bool inb = (fxf >= 0.0f) & (fxf < (float)IW) & (fyf >= 0.0f) & (fyf < (float)IH)
                       & (!hit);
            if (inb) atomicAdd(&img[(int)fyf * IW + (int)fxf], cosv);
        }
    }
}

__global__ __launch_bounds__(256) void reduce_kernel(
    const float* __restrict__ imgs, int K, float* __restrict__ out)
{
    int i = blockIdx.x * 256 + threadIdx.x;
    float v = 0.0f;
    for (int k = 0; k < K; k++) v += imgs[(size_t)k * NPIX + i];
    out[i] = v;
}

extern "C" void kernel_launch(void* const* d_in, const int* in_sizes, int n_in,
                              void* d_out, int out_size, void* d_ws, size_t ws_size,
                              hipStream_t stream) {
    const float* sources = (const float*)d_in[0];
    const float* mpts    = (const float*)d_in[1];
    const float* mnrm    = (const float*)d_in[2];
    const float* mpos    = (const float*)d_in[3];
    const float* mrot    = (const float*)d_in[4];
    const float* cp1     = (const float*)d_in[5];
    const float* cp2     = (const float*)d_in[6];
    const float* crad    = (const float*)d_in[7];
    const float* bp1     = (const float*)d_in[8];
    const float* bp2     = (const float*)d_in[9];
    const float* spp     = (const float*)d_in[10];
    const float* spn     = (const float*)d_in[11];

    const size_t ARENA_BYTES = (size_t)NM * NS * NP * 4u;            // 64 MiB
    const size_t GIMG_BYTES  = (size_t)GSPLIT * NPIX * 4u;           //  8 MiB
    const size_t CNT_BYTES   = 4096;
    const size_t BND_BYTES   = 1024;
    const size_t MSK_BYTES   = (size_t)NM * NS * 4u;                 // 32 KiB
    const size_t FIXED = ARENA_BYTES + GIMG_BYTES + CNT_BYTES + BND_BYTES + MSK_BYTES;

    // Adaptive descriptor capacity: as large as ws allows, down to 2048.
    int maxd = 0;
    for (int md = 16384; md >= 2048; md >>= 1) {
        if (FIXED + (size_t)NTILE * md * 8u <= ws_size) { maxd = md; break; }
    }

    if (maxd > 0) {
        // ---------- binning pipeline ----------
        char* p = (char*)d_ws;
        unsigned* arena    = (unsigned*)p;                  p += ARENA_BYTES;
        uint2*    desc     = (uint2*)p;                     p += (size_t)NTILE * maxd * 8u;
        float*    gimg     = (float*)p;                     p += GIMG_BYTES;
        unsigned* galloc   = (unsigned*)p;                  // [0] = alloc, [256..] desc_cnt
        unsigned* desc_cnt = galloc + 256;                  p += CNT_BYTES;
        float4*   bounds   = (float4*)p;                    p += BND_BYTES;
        unsigned* masks    = (unsigned*)p;

        hipMemsetAsync(galloc, 0, CNT_BYTES, stream);
        hipMemsetAsync(d_out, 0, (size_t)NPIX * sizeof(float), stream);  // direct-flush target

        mirror_bounds_kernel<<<NM, 256, 0, stream>>>(mpts, mpos, mrot, bounds);
        mask_kernel<<<(NM * NS + 255) / 256, 256, 0, stream>>>(
            sources, cp1, cp2, crad, bp1, bp2, bounds, masks);

        dim3 grid(NP / 256, NS / SPT, NM);   // (8,16,64) = 8192 blocks
        render_bin_kernel<<<grid, 256, 0, stream>>>(
            sources, mpts, mnrm, mpos, mrot, cp1, cp2, crad, bp1, bp2, spp, spn,
            masks, arena, desc, desc_cnt, galloc, (float*)d_out, maxd);

        dim3 grid2(NTILE, GSPLIT);           // 256 tiles x 8 splits
        tile_accum_kernel<<<grid2, 256, 0, stream>>>(arena, desc, desc_cnt, maxd, gimg);

        reduce_bin_kernel<<<NPIX / 256, 256, 0, stream>>>(gimg, (float*)d_out);
    } else {
        // ---------- R7 fallback: direct atomics with K privatized images ----------
        const size_t IMG_BYTES = (size_t)NPIX * sizeof(float);
        const size_t AUX_BYTES = 1024 + (size_t)NM * NS * sizeof(unsigned);
        int K = 0;
        for (int k = 8; k >= 1; k >>= 1) {
            if ((size_t)k * IMG_BYTES + AUX_BYTES <= ws_size) { K = k; break; }
        }
        float* imgs;
        char*  aux;
        if (K >= 1) {
            imgs = (float*)d_ws;
            aux  = (char*)d_ws + (size_t)K * IMG_BYTES;
            hipMemsetAsync(imgs, 0, (size_t)K * IMG_BYTES, stream);
        } else {
            K    = 1;
            imgs = (float*)d_out;
            aux  = (char*)d_ws;
            hipMemsetAsync(imgs, 0, IMG_BYTES, stream);
        }
        float4*   bounds = (float4*)aux;
        unsigned* masks  = (unsigned*)(aux + 1024);

        mirror_bounds_kernel<<<NM, 256, 0, stream>>>(mpts, mpos, mrot, bounds);
        mask_kernel<<<(NM * NS + 255) / 256, 256, 0, stream>>>(
            sources, cp1, cp2, crad, bp1, bp2, bounds, masks);

        dim3 grid(NP / 256, NS / SPT, NM);
        render_kernel<<<grid, 256, 0, stream>>>(sources, mpts, mnrm, mpos, mrot,
                                                cp1, cp2, crad, bp1, bp2, spp, spn,
                                                masks, imgs, K);
        if (imgs != (float*)d_out) {
            reduce_kernel<<<NPIX / 256, 256, 0, stream>>>(imgs, K, (float*)d_out);
        }
    }
}

// Round 10
// 422.058 us; speedup vs baseline: 2.4749x; 1.3831x over previous
//
#include <hip/hip_runtime.h>

// S,P,M=(128,2048,64), NC,NB=(16,8), H,W=512, EXTENT=12, EPS=1e-9
#define NS   128
#define NP   2048
#define NM   64
#define NCYL 16
#define NBOX 8
#define IH   512
#define IW   512
#define NPIX (IH*IW)
#define FEXT 12.0f
#define FEPS 1e-9f
#define PXSCALE ((float)IW / (2.0f * FEXT))
#define PRUNE_MARGIN 0.05f
#define SPT  8      // sources per thread
#define NTILE 256   // 16x16 grid of 32x32-pixel tiles
#define GSPLIT 8    // pass-2 blocks per tile

__device__ __forceinline__ float frcp(float x)   { return __builtin_amdgcn_rcpf(x); }
__device__ __forceinline__ float frsq(float x)   { return __builtin_amdgcn_rsqf(x); }
__device__ __forceinline__ float fsqrt_(float x) { return __builtin_amdgcn_sqrtf(x); }
__device__ __forceinline__ float clamp01(float x){ return fminf(fmaxf(x, 0.0f), 1.0f); }

// ---------------- Pre-pass A: per-mirror bounding sphere of transformed points
__global__ __launch_bounds__(256) void mirror_bounds_kernel(
    const float* __restrict__ mpts, const float* __restrict__ mpos,
    const float* __restrict__ mrot, float4* __restrict__ bounds)
{
    const int m = blockIdx.x;
    const int t = threadIdx.x;
    float R0 = mrot[m*9+0], R1 = mrot[m*9+1], R2 = mrot[m*9+2];
    float R3 = mrot[m*9+3], R4 = mrot[m*9+4], R5 = mrot[m*9+5];
    float R6 = mrot[m*9+6], R7 = mrot[m*9+7], R8 = mrot[m*9+8];
    float posx = mpos[m*3+0], posy = mpos[m*3+1], posz = mpos[m*3+2];

    float mnx = 1e30f, mny = 1e30f, mnz = 1e30f;
    float mxx = -1e30f, mxy = -1e30f, mxz = -1e30f;
    for (int i = t; i < NP; i += 256) {
        long id = ((long)m * NP + i) * 3;
        float px = mpts[id+0], py = mpts[id+1], pz = mpts[id+2];
        float tx = R0*px + R1*py + R2*pz + posx;
        float ty = R3*px + R4*py + R5*pz + posy;
        float tz = R6*px + R7*py + R8*pz + posz;
        mnx = fminf(mnx, tx); mny = fminf(mny, ty); mnz = fminf(mnz, tz);
        mxx = fmaxf(mxx, tx); mxy = fmaxf(mxy, ty); mxz = fmaxf(mxz, tz);
    }
    __shared__ float red[6][256];
    red[0][t] = mnx; red[1][t] = mny; red[2][t] = mnz;
    red[3][t] = mxx; red[4][t] = mxy; red[5][t] = mxz;
    __syncthreads();
    for (int off = 128; off > 0; off >>= 1) {
        if (t < off) {
            red[0][t] = fminf(red[0][t], red[0][t+off]);
            red[1][t] = fminf(red[1][t], red[1][t+off]);
            red[2][t] = fminf(red[2][t], red[2][t+off]);
            red[3][t] = fmaxf(red[3][t], red[3][t+off]);
            red[4][t] = fmaxf(red[4][t], red[4][t+off]);
            red[5][t] = fmaxf(red[5][t], red[5][t+off]);
        }
        __syncthreads();
    }
    if (t == 0) {
        float cx = 0.5f*(red[0][0]+red[3][0]);
        float cy = 0.5f*(red[1][0]+red[4][0]);
        float cz = 0.5f*(red[2][0]+red[5][0]);
        float hx = 0.5f*(red[3][0]-red[0][0]);
        float hy = 0.5f*(red[4][0]-red[1][0]);
        float hz = 0.5f*(red[5][0]-red[2][0]);
        float r  = sqrtf(hx*hx + hy*hy + hz*hz);
        bounds[m] = make_float4(cx, cy, cz, r);
    }
}

// ---------------- Pre-pass B: per-(mirror,source) occluder mask (conservative)
__global__ __launch_bounds__(256) void mask_kernel(
    const float* __restrict__ sources,
    const float* __restrict__ cp1g, const float* __restrict__ cp2g,
    const float* __restrict__ crad,
    const float* __restrict__ bp1g, const float* __restrict__ bp2g,
    const float4* __restrict__ bounds, unsigned* __restrict__ masks)
{
    int pair = blockIdx.x * 256 + threadIdx.x;
    if (pair >= NM * NS) return;
    int m = pair / NS;
    int s = pair - m * NS;

    float4 bd = bounds[m];
    float cx = bd.x, cy = bd.y, cz = bd.z;
    float rm = bd.w + PRUNE_MARGIN;
    float sx = sources[s*3+0], sy = sources[s*3+1], sz = sources[s*3+2];

    float d1x = sx - cx, d1y = sy - cy, d1z = sz - cz;
    float a = d1x*d1x + d1y*d1y + d1z*d1z;

    unsigned mask = 0;

    for (int c = 0; c < NCYL; c++) {
        float p2x = cp1g[c*3+0], p2y = cp1g[c*3+1], p2z = cp1g[c*3+2];
        float d2x = cp2g[c*3+0] - p2x, d2y = cp2g[c*3+1] - p2y, d2z = cp2g[c*3+2] - p2z;
        float rx = cx - p2x, ry = cy - p2y, rz = cz - p2z;
        float e = d2x*d2x + d2y*d2y + d2z*d2z;
        float f = d2x*rx + d2y*ry + d2z*rz;
        float cc = d1x*rx + d1y*ry + d1z*rz;
        float b = d1x*d2x + d1y*d2y + d1z*d2z;
        float denom = a*e - b*b;
        float sN = (denom > 1e-6f) ? clamp01((b*f - cc*e) / denom) : 0.0f;
        float tN = (b*sN + f) / e;
        if (tN < 0.0f)      { tN = 0.0f; sN = clamp01(-cc / a); }
        else if (tN > 1.0f) { tN = 1.0f; sN = clamp01((b - cc) / a); }
        float gx = (cx + d1x*sN) - (p2x + d2x*tN);
        float gy = (cy + d1y*sN) - (p2y + d2y*tN);
        float gz = (cz + d1z*sN) - (p2z + d2z*tN);
        float dist2 = gx*gx + gy*gy + gz*gz;
        float thr = crad[c] + rm;
        if (dist2 <= thr*thr) mask |= (1u << c);
    }

    float ivx = 1.0f / ((fabsf(d1x) < FEPS) ? FEPS : d1x);
    float ivy = 1.0f / ((fabsf(d1y) < FEPS) ? FEPS : d1y);
    float ivz = 1.0f / ((fabsf(d1z) < FEPS) ? FEPS : d1z);
    for (int b = 0; b < NBOX; b++) {
        float lx = bp1g[b*3+0] - rm, ly = bp1g[b*3+1] - rm, lz = bp1g[b*3+2] - rm;
        float hx = bp2g[b*3+0] + rm, hy = bp2g[b*3+1] + rm, hz = bp2g[b*3+2] + rm;
        float t0x = (lx - cx) * ivx, t1x = (hx - cx) * ivx;
        float t0y = (ly - cy) * ivy, t1y = (hy - cy) * ivy;
        float t0z = (lz - cz) * ivz, t1z = (hz - cz) * ivz;
        float tmin = fmaxf(fmaxf(fminf(t0x,t1x), fminf(t0y,t1y)), fminf(t0z,t1z));
        float tmax = fminf(fminf(fmaxf(t0x,t1x), fmaxf(t0y,t1y)), fmaxf(t0z,t1z));
        if (fmaxf(tmin, 0.0f) <= fminf(tmax, 1.0f)) mask |= (1u << (16 + b));
    }

    masks[pair] = mask;
}

// ================= BINNING PIPELINE (pass 1): rays -> tile-grouped records
__global__ __launch_bounds__(256) void render_bin_kernel(
    const float* __restrict__ sources, const float* __restrict__ mpts,
    const float* __restrict__ mnrm,    const float* __restrict__ mpos,
    const float* __restrict__ mrot,
    const float* __restrict__ cp1g, const float* __restrict__ cp2g,
    const float* __restrict__ crad, const float* __restrict__ bp1g,
    const float* __restrict__ bp2g, const float* __restrict__ spp,
    const float* __restrict__ spn,  const unsigned* __restrict__ masks,
    unsigned* __restrict__ arena, uint2* __restrict__ desc,
    unsigned* __restrict__ desc_cnt, unsigned* __restrict__ galloc,
    float* __restrict__ img_direct, int maxd)
{
    __shared__ float4 s_cyl[NCYL][2];
    __shared__ float4 s_box[NBOX][2];
    __shared__ unsigned s_cnt[NTILE];
    __shared__ unsigned s_inc[NTILE];
    __shared__ unsigned s_scratch[256 * SPT];
    __shared__ unsigned s_base;
    __shared__ unsigned s_of[32][2];
    __shared__ unsigned s_ofn;

    const int t  = threadIdx.x;
    const int n  = blockIdx.x * 256 + t;
    const int s0 = blockIdx.y * SPT;
    const int m  = blockIdx.z;

    const long idx = ((long)m * NP + n) * 3;
    float px = mpts[idx+0], py = mpts[idx+1], pz = mpts[idx+2];
    float nx = mnrm[idx+0], ny = mnrm[idx+1], nz = mnrm[idx+2];

    s_cnt[t] = 0;   // 256 threads == NTILE
    if (t == 0) s_ofn = 0;
    if (t < NCYL) {
        float p1x = cp1g[t*3+0], p1y = cp1g[t*3+1], p1z = cp1g[t*3+2];
        float axx = cp2g[t*3+0] - p1x;
        float axy = cp2g[t*3+1] - p1y;
        float axz = cp2g[t*3+2] - p1z;
        float L   = sqrtf(axx*axx + axy*axy + axz*axz);
        float inv = 1.0f / (L + FEPS);
        float r   = crad[t];
        s_cyl[t][0] = make_float4(p1x, p1y, p1z, L);
        s_cyl[t][1] = make_float4(axx*inv, axy*inv, axz*inv, r*r);
    } else if (t < NCYL + NBOX) {
        int b = t - NCYL;
        s_box[b][0] = make_float4(bp1g[b*3+0], bp1g[b*3+1], bp1g[b*3+2], 0.0f);
        s_box[b][1] = make_float4(bp2g[b*3+0], bp2g[b*3+1], bp2g[b*3+2], 0.0f);
    }
    __syncthreads();

    float R0 = mrot[m*9+0], R1 = mrot[m*9+1], R2 = mrot[m*9+2];
    float R3 = mrot[m*9+3], R4 = mrot[m*9+4], R5 = mrot[m*9+5];
    float R6 = mrot[m*9+6], R7 = mrot[m*9+7], R8 = mrot[m*9+8];
    float posx = mpos[m*3+0], posy = mpos[m*3+1], posz = mpos[m*3+2];
    float sppx = spp[0], sppy = spp[1], sppz = spp[2];
    float spnx = spn[0], spny = spn[1], spnz = spn[2];

    float tpx = R0*px + R1*py + R2*pz + posx;
    float tpy = R3*px + R4*py + R5*pz + posy;
    float tpz = R6*px + R7*py + R8*pz + posz;
    float tnx = R0*nx + R1*ny + R2*nz;
    float tny = R3*nx + R4*ny + R5*nz;
    float tnz = R6*nx + R7*ny + R8*nz;

    float num = (sppx-tpx)*spnx + (sppy-tpy)*spny + (sppz-tpz)*spnz;

    unsigned rec[SPT];
    unsigned rank[SPT];
    int      tileid[SPT];
    unsigned vmask = 0;

    #pragma unroll
    for (int j = 0; j < SPT; j++) {
        const int s = s0 + j;
        float sx = sources[s*3+0], sy = sources[s*3+1], sz = sources[s*3+2];

        float dx = tpx - sx, dy = tpy - sy, dz = tpz - sz;
        float il = frsq(dx*dx + dy*dy + dz*dz);
        dx *= il; dy *= il; dz *= il;
        float ux = -dx, uy = -dy, uz = -dz;

        unsigned pm = masks[(unsigned)m * NS + (unsigned)s];
        pm = __builtin_amdgcn_readfirstlane(pm);
        unsigned cmask = pm & 0xFFFFu;
        unsigned bmask = (pm >> 16) & 0xFFu;

        bool hit = false;

        while (cmask) {
            int c = __builtin_ctz(cmask);
            cmask &= cmask - 1;
            float4 c0 = s_cyl[c][0];
            float4 c1 = s_cyl[c][1];
            float ocx = tpx - c0.x, ocy = tpy - c0.y, ocz = tpz - c0.z;
            float oa  = ocx*c1.x + ocy*c1.y + ocz*c1.z;
            float Cc  = ocx*ocx + ocy*ocy + ocz*ocz - oa*oa - c1.w;
            float ua  = ux*c1.x + uy*c1.y + uz*c1.z;
            float ocu = ux*ocx + uy*ocy + uz*ocz;
            float Bh  = fmaf(-oa, ua, ocu);
            float A   = fmaf(-ua, ua, 1.0f);
            float disc = fmaf(Bh, Bh, -(A*Cc));
            float sq   = fsqrt_(fmaxf(disc, 0.0f));
            float Ah   = A + 0.5f*FEPS;
            float q1   = -Bh - sq;
            float q2   = -Bh + sq;
            float oaA  = oa * Ah;
            float LA   = c0.w * Ah;
            float epsA = FEPS * Ah;
            float ax1A = fmaf(q1, ua, oaA);
            float ax2A = fmaf(q2, ua, oaA);
            bool dpos  = disc > 0.0f;
            hit = hit | (dpos & (q1 > epsA) & (ax1A >= 0.0f) & (ax1A <= LA))
                      | (dpos & (q2 > epsA) & (ax2A >= 0.0f) & (ax2A <= LA));
        }

        if (bmask) {
            float ivx = frcp((fabsf(ux) < FEPS) ? FEPS : ux);
            float ivy = frcp((fabsf(uy) < FEPS) ? FEPS : uy);
            float ivz = frcp((fabsf(uz) < FEPS) ? FEPS : uz);
            while (bmask) {
                int b = __builtin_ctz(bmask);
                bmask &= bmask - 1;
                float4 b1 = s_box[b][0];
                float4 b2 = s_box[b][1];
                float t0x = (b1.x - tpx) * ivx, t1x = (b2.x - tpx) * ivx;
                float t0y = (b1.y - tpy) * ivy, t1y = (b2.y - tpy) * ivy;
                float t0z = (b1.z - tpz) * ivz, t1z = (b2.z - tpz) * ivz;
                float tmin = fmaxf(fmaxf(fminf(t0x,t1x), fminf(t0y,t1y)), fminf(t0z,t1z));
                float tmax = fminf(fminf(fmaxf(t0x,t1x), fmaxf(t0y,t1y)), fmaxf(t0z,t1z));
                hit = hit | (tmax >= fmaxf(tmin, FEPS));
            }
        }

        float dn = dx*tnx + dy*tny + dz*tnz;
        float rx = fmaf(-2.0f*dn, tnx, dx);
        float ry = fmaf(-2.0f*dn, tny, dy);
        float rz = fmaf(-2.0f*dn, tnz, dz);
        float cosv  = fabsf(dn);
        float denom = rx*spnx + ry*spny + rz*spnz;
        float tt = num * frcp(denom + FEPS);
        float qx = fmaf(tt, rx, tpx);
        float qy = fmaf(tt, ry, tpy);
        float fx = (qx + FEXT) * PXSCALE;
        float fy = (qy + FEXT) * PXSCALE;
        float fxf = floorf(fx), fyf = floorf(fy);
        bool inb = (fxf >= 0.0f) & (fxf < (float)IW) & (fyf >= 0.0f) & (fyf < (float)IH)
                   & (!hit);
        if (inb) {
            int ix = (int)fxf, iy = (int)fyf;
            unsigned pix = (unsigned)(iy * IW + ix);
            unsigned q = (unsigned)(cosv * 16383.0f + 0.5f);
            if (q > 16383u) q = 16383u;
            rec[j]    = (pix << 14) | q;
            int tl    = ((iy >> 5) << 4) | (ix >> 5);
            tileid[j] = tl;
            rank[j]   = atomicAdd(&s_cnt[tl], 1u);
            vmask    |= (1u << j);
        }
    }
    __syncthreads();

    // Inclusive scan of s_cnt -> s_inc (Hillis-Steele, 256 entries).
    s_inc[t] = s_cnt[t];
    __syncthreads();
    for (int st = 1; st < NTILE; st <<= 1) {
        unsigned v = (t >= st) ? s_inc[t - st] : 0u;
        __syncthreads();
        s_inc[t] += v;
        __syncthreads();
    }
    unsigned total = s_inc[NTILE - 1];
    if (t == 0) s_base = total ? atomicAdd(galloc, total) : 0u;
    __syncthreads();

    // Stage records grouped by tile in LDS.
    #pragma unroll
    for (int j = 0; j < SPT; j++) {
        if (vmask & (1u << j)) {
            int tl = tileid[j];
            unsigned off = s_inc[tl] - s_cnt[tl];
            s_scratch[off + rank[j]] = rec[j];
        }
    }
    __syncthreads();

    // Coalesced copy to global arena.
    unsigned base = s_base;
    for (unsigned i = t; i < total; i += 256) arena[base + i] = s_scratch[i];

    // Emit one descriptor per non-empty tile (thread t owns tile t).
    unsigned c = s_cnt[t];
    if (c > 0) {
        unsigned off  = s_inc[t] - c;
        unsigned slot = atomicAdd(&desc_cnt[t], 1u);
        if (slot < (unsigned)maxd) {
            desc[(size_t)t * maxd + slot] = make_uint2(base + off, ((unsigned)t << 16) | c);
        } else {
            unsigned k = atomicAdd(&s_ofn, 1u);
            if (k < 32u) { s_of[k][0] = off; s_of[k][1] = c; }
            else {
                for (unsigned q = 0; q < c; q++) {
                    unsigned r = s_scratch[off + q];
                    atomicAdd(&img_direct[r >> 14], (float)(r & 16383u) * (1.0f/16383.0f));
                }
            }
        }
    }
    __syncthreads();

    // Cooperative (256-wide) flush of overflowed segments.
    unsigned nof = s_ofn < 32u ? s_ofn : 32u;
    for (unsigned k = 0; k < nof; k++) {
        unsigned off = s_of[k][0], cc = s_of[k][1];
        for (unsigned i = t; i < cc; i += 256) {
            unsigned r = s_scratch[off + i];
            atomicAdd(&img_direct[r >> 14], (float)(r & 16383u) * (1.0f/16383.0f));
        }
    }
}

// ================= pass 2: per-tile LDS accumulation with deep MLP
// 512 threads (8 waves) x 8 splits = 64 streams/tile; 8-deep independent
// record loads per round break the load->waitcnt->atomic serialization.
__global__ __launch_bounds__(512) void tile_accum_kernel(
    const unsigned* __restrict__ arena, const uint2* __restrict__ desc,
    const unsigned* __restrict__ desc_cnt, int maxd, float* __restrict__ gimg)
{
    __shared__ float tile[1024];
    const int t    = blockIdx.x;   // tile id
    const int g    = blockIdx.y;   // split group (0..7)
    const int tid  = threadIdx.x;
    const int wid  = tid >> 6;     // wave id (0..7)
    const int lane = tid & 63;

    for (int i = tid; i < 1024; i += 512) tile[i] = 0.0f;
    __syncthreads();

    unsigned nd = desc_cnt[t];
    if (nd > (unsigned)maxd) nd = (unsigned)maxd;

    const uint2* __restrict__ dbase = desc + (size_t)t * maxd;
    const unsigned sid = (unsigned)(g * 8 + wid);   // stream 0..63
    const unsigned NSTREAM = 64;

    // Walk this stream's descriptors (d = sid + k*64) in groups of 64:
    // one lane-parallel gather fetches 64 descriptors at once.
    for (unsigned kbase = 0; sid + kbase * NSTREAM < nd; kbase += 64) {
        unsigned didx = sid + (kbase + (unsigned)lane) * NSTREAM;
        uint2 ddl = (didx < nd) ? dbase[didx] : make_uint2(0u, 0u);

        for (unsigned j = 0; j < 64; j++) {
            if (sid + (kbase + j) * NSTREAM >= nd) break;
            unsigned start = (unsigned)__shfl((int)ddl.x, (int)j, 64);
            unsigned cw    = ((unsigned)__shfl((int)ddl.y, (int)j, 64)) & 0xFFFFu;

            // 8-deep unrolled record gather: 8 independent loads in flight.
            for (unsigned i0 = 0; i0 < cw; i0 += 512) {
                unsigned idx0 = i0 + (unsigned)lane;
                unsigned rcd[8];
                #pragma unroll
                for (int k = 0; k < 8; k++) {
                    unsigned ii = idx0 + (unsigned)(k * 64);
                    unsigned cl = ii < cw ? ii : (cw - 1u);  // clamped dup (cheap, same line)
                    rcd[k] = arena[start + cl];
                }
                #pragma unroll
                for (int k = 0; k < 8; k++) {
                    unsigned ii = idx0 + (unsigned)(k * 64);
                    if (ii < cw) {
                        unsigned pix = rcd[k] >> 14;
                        float val = (float)(rcd[k] & 16383u) * (1.0f/16383.0f);
                        unsigned ix = pix & 511u, iy = pix >> 9;
                        unsigned lp = ((iy & 31u) << 5) | (ix & 31u);
                        atomicAdd(&tile[lp], val);   // LDS atomic — per-CU
                    }
                }
            }
        }
    }
    __syncthreads();

    // tiles partition the image; (t,g) unique -> plain stores, no atomics
    const unsigned ty = t >> 4, tx = t & 15;
    float* out = gimg + (size_t)g * NPIX;
    for (int i = tid; i < 1024; i += 512) {
        unsigned gy = ty * 32 + (i >> 5);
        unsigned gx = tx * 32 + (i & 31);
        out[gy * IW + gx] = tile[i];
    }
}

__global__ __launch_bounds__(256) void reduce_bin_kernel(
    const float* __restrict__ gimg, float* __restrict__ out)
{
    int i = blockIdx.x * 256 + threadIdx.x;
    float v = out[i];   // direct-flush atomics already landed in out
    #pragma unroll
    for (int g = 0; g < GSPLIT; g++) v += gimg[(size_t)g * NPIX + i];
    out[i] = v;
}

// ================= R7 fallback (ws too small): direct-atomic pipeline
__global__ __launch_bounds__(256) void render_kernel(
    const float* __restrict__ sources, const float* __restrict__ mpts,
    const float* __restrict__ mnrm,    const float* __restrict__ mpos,
    const float* __restrict__ mrot,
    const float* __restrict__ cp1g, const float* __restrict__ cp2g,
    const float* __restrict__ crad, const float* __restrict__ bp1g,
    const float* __restrict__ bp2g, const float* __restrict__ spp,
    const float* __restrict__ spn,  const unsigned* __restrict__ masks,
    float* __restrict__ imgs, int K)
{
    __shared__ float4 s_cyl[NCYL][2];
    __shared__ float4 s_box[NBOX][2];

    const int t  = threadIdx.x;
    const int n  = blockIdx.x * 256 + t;
    const int s0 = blockIdx.y * SPT;
    const int m  = blockIdx.z;

    const long idx = ((long)m * NP + n) * 3;
    float px = mpts[idx+0], py = mpts[idx+1], pz = mpts[idx+2];
    float nx = mnrm[idx+0], ny = mnrm[idx+1], nz = mnrm[idx+2];

    if (t < NCYL) {
        float p1x = cp1g[t*3+0], p1y = cp1g[t*3+1], p1z = cp1g[t*3+2];
        float axx = cp2g[t*3+0] - p1x;
        float axy = cp2g[t*3+1] - p1y;
        float axz = cp2g[t*3+2] - p1z;
        float L   = sqrtf(axx*axx + axy*axy + axz*axz);
        float inv = 1.0f / (L + FEPS);
        float r   = crad[t];
        s_cyl[t][0] = make_float4(p1x, p1y, p1z, L);
        s_cyl[t][1] = make_float4(axx*inv, axy*inv, axz*inv, r*r);
    } else if (t < NCYL + NBOX) {
        int b = t - NCYL;
        s_box[b][0] = make_float4(bp1g[b*3+0], bp1g[b*3+1], bp1g[b*3+2], 0.0f);
        s_box[b][1] = make_float4(bp2g[b*3+0], bp2g[b*3+1], bp2g[b*3+2], 0.0f);
    }
    __syncthreads();

    float R0 = mrot[m*9+0], R1 = mrot[m*9+1], R2 = mrot[m*9+2];
    float R3 = mrot[m*9+3], R4 = mrot[m*9+4], R5 = mrot[m*9+5];
    float R6 = mrot[m*9+6], R7 = mrot[m*9+7], R8 = mrot[m*9+8];
    float posx = mpos[m*3+0], posy = mpos[m*3+1], posz = mpos[m*3+2];
    float sppx = spp[0], sppy = spp[1], sppz = spp[2];
    float spnx = spn[0], spny = spn[1], spnz = spn[2];

    float tpx = R0*px + R1*py + R2*pz + posx;
    float tpy = R3*px + R4*py + R5*pz + posy;
    float tpz = R6*px + R7*py + R8*pz + posz;
    float tnx = R0*nx + R1*ny + R2*nz;
    float tny = R3*nx + R4*ny + R5*nz;
    float tnz = R6*nx + R7*ny + R8*nz;

    float num = (sppx-tpx)*spnx + (sppy-tpy)*spny + (sppz-tpz)*spnz;

    int linb = blockIdx.x + (int)gridDim.x * (blockIdx.y + (int)gridDim.y * blockIdx.z);
    float* __restrict__ img = imgs + (size_t)(linb % K) * NPIX;

    for (int j = 0; j < SPT; j++) {
        const int s = s0 + j;
        float sx = sources[s*3+0], sy = sources[s*3+1], sz = sources[s*3+2];

        float dx = tpx - sx, dy = tpy - sy, dz = tpz - sz;
        float il = frsq(dx*dx + dy*dy + dz*dz);
        dx *= il; dy *= il; dz *= il;
        float ux = -dx, uy = -dy, uz = -dz;

        unsigned pm = masks[(unsigned)m * NS + (unsigned)s];
        pm = __builtin_amdgcn_readfirstlane(pm);
        unsigned cmask = pm & 0xFFFFu;
        unsigned bmask = (pm >> 16) & 0xFFu;

        bool hit = false;

        while (cmask) {
            int c = __builtin_ctz(cmask);
            cmask &= cmask - 1;
            float4 c0 = s_cyl[c][0];
            float4 c1 = s_cyl[c][1];
            float ocx = tpx - c0.x, ocy = tpy - c0.y, ocz = tpz - c0.z;
            float oa  = ocx*c1.x + ocy*c1.y + ocz*c1.z;
            float Cc  = ocx*ocx + ocy*ocy + ocz*ocz - oa*oa - c1.w;
            float ua  = ux*c1.x + uy*c1.y + uz*c1.z;
            float ocu = ux*ocx + uy*ocy + uz*ocz;
            float Bh  = fmaf(-oa, ua, ocu);
            float A   = fmaf(-ua, ua, 1.0f);
            float disc = fmaf(Bh, Bh, -(A*Cc));
            float sq   = fsqrt_(fmaxf(disc, 0.0f));
            float Ah   = A + 0.5f*FEPS;
            float q1   = -Bh - sq;
            float q2   = -Bh + sq;
            float oaA  = oa * Ah;
            float LA   = c0.w * Ah;
            float epsA = FEPS * Ah;
            float ax1A = fmaf(q1, ua, oaA);
            float ax2A = fmaf(q2, ua, oaA);
            bool dpos  = disc > 0.0f;
            hit = hit | (dpos & (q1 > epsA) & (ax1A >= 0.0f) & (ax1A <= LA))
                      | (dpos & (q2 > epsA) & (ax2A >= 0.0f) & (ax2A <= LA));
        }

        if (bmask) {
            float ivx = frcp((fabsf(ux) < FEPS) ? FEPS : ux);
            float ivy = frcp((fabsf(uy) < FEPS) ? FEPS : uy);
            float ivz = frcp((fabsf(uz) < FEPS) ? FEPS : uz);
            while (bmask) {
                int b = __builtin_ctz(bmask);
                bmask &= bmask - 1;
                float4 b1 = s_box[b][0];
                float4 b2 = s_box[b][1];
                float t0x = (b1.x - tpx) * ivx, t1x = (b2.x - tpx) * ivx;
                float t0y = (b1.y - tpy) * ivy, t1y = (b2.y - tpy) * ivy;
                float t0z = (b1.z - tpz) * ivz, t1z = (b2.z - tpz) * ivz;
                float tmin = fmaxf(fmaxf(fminf(t0x,t1x), fminf(t0y,t1y)), fminf(t0z,t1z));
                float tmax = fminf(fminf(fmaxf(t0x,t1x), fmaxf(t0y,t1y)), fmaxf(t0z,t1z));
                hit = hit | (tmax >= fmaxf(tmin, FEPS));
            }
        }

        {
            float dn = dx*tnx + dy*tny + dz*tnz;
            float rx = fmaf(-2.0f*dn, tnx, dx);
            float ry = fmaf(-2.0f*dn, tny, dy);
            float rz = fmaf(-2.0f*dn, tnz, dz);
            float cosv  = fabsf(dn);
            float denom = rx*spnx + ry*spny + rz*spnz;
            float tt = num * frcp(denom + FEPS);
            float qx = fmaf(tt, rx, tpx);
            float qy = fmaf(tt, ry, tpy);
            float fx = (qx + FEXT) * PXSCALE;
            float fy = (qy + FEXT) * PXSCALE;
            float fxf = floorf(fx), fyf = floorf(fy);
            bool inb = (fxf >= 0.0f) & (fxf < (float)IW) & (fyf >= 0.0f) & (fyf < (float)IH)
                       & (!hit);
            if (inb) atomicAdd(&img[(int)fyf * IW + (int)fxf], cosv);
        }
    }
}

__global__ __launch_bounds__(256) void reduce_kernel(
    const float* __restrict__ imgs, int K, float* __restrict__ out)
{
    int i = blockIdx.x * 256 + threadIdx.x;
    float v = 0.0f;
    for (int k = 0; k < K; k++) v += imgs[(size_t)k * NPIX + i];
    out[i] = v;
}

extern "C" void kernel_launch(void* const* d_in, const int* in_sizes, int n_in,
                              void* d_out, int out_size, void* d_ws, size_t ws_size,
                              hipStream_t stream) {
    const float* sources = (const float*)d_in[0];
    const float* mpts    = (const float*)d_in[1];
    const float* mnrm    = (const float*)d_in[2];
    const float* mpos    = (const float*)d_in[3];
    const float* mrot    = (const float*)d_in[4];
    const float* cp1     = (const float*)d_in[5];
    const float* cp2     = (const float*)d_in[6];
    const float* crad    = (const float*)d_in[7];
    const float* bp1     = (const float*)d_in[8];
    const float* bp2     = (const float*)d_in[9];
    const float* spp     = (const float*)d_in[10];
    const float* spn     = (const float*)d_in[11];

    const size_t ARENA_BYTES = (size_t)NM * NS * NP * 4u;            // 64 MiB
    const size_t GIMG_BYTES  = (size_t)GSPLIT * NPIX * 4u;           //  8 MiB
    const size_t CNT_BYTES   = 4096;
    const size_t BND_BYTES   = 1024;
    const size_t MSK_BYTES   = (size_t)NM * NS * 4u;                 // 32 KiB
    const size_t FIXED = ARENA_BYTES + GIMG_BYTES + CNT_BYTES + BND_BYTES + MSK_BYTES;

    // Adaptive descriptor capacity: as large as ws allows, down to 2048.
    int maxd = 0;
    for (int md = 16384; md >= 2048; md >>= 1) {
        if (FIXED + (size_t)NTILE * md * 8u <= ws_size) { maxd = md; break; }
    }

    if (maxd > 0) {
        // ---------- binning pipeline ----------
        char* p = (char*)d_ws;
        unsigned* arena    = (unsigned*)p;                  p += ARENA_BYTES;
        uint2*    desc     = (uint2*)p;                     p += (size_t)NTILE * maxd * 8u;
        float*    gimg     = (float*)p;                     p += GIMG_BYTES;
        unsigned* galloc   = (unsigned*)p;                  // [0] = alloc, [256..] desc_cnt
        unsigned* desc_cnt = galloc + 256;                  p += CNT_BYTES;
        float4*   bounds   = (float4*)p;                    p += BND_BYTES;
        unsigned* masks    = (unsigned*)p;

        hipMemsetAsync(galloc, 0, CNT_BYTES, stream);
        hipMemsetAsync(d_out, 0, (size_t)NPIX * sizeof(float), stream);  // direct-flush target

        mirror_bounds_kernel<<<NM, 256, 0, stream>>>(mpts, mpos, mrot, bounds);
        mask_kernel<<<(NM * NS + 255) / 256, 256, 0, stream>>>(
            sources, cp1, cp2, crad, bp1, bp2, bounds, masks);

        dim3 grid(NP / 256, NS / SPT, NM);   // (8,16,64) = 8192 blocks
        render_bin_kernel<<<grid, 256, 0, stream>>>(
            sources, mpts, mnrm, mpos, mrot, cp1, cp2, crad, bp1, bp2, spp, spn,
            masks, arena, desc, desc_cnt, galloc, (float*)d_out, maxd);

        dim3 grid2(NTILE, GSPLIT);           // 256 tiles x 8 splits, 512 threads
        tile_accum_kernel<<<grid2, 512, 0, stream>>>(arena, desc, desc_cnt, maxd, gimg);

        reduce_bin_kernel<<<NPIX / 256, 256, 0, stream>>>(gimg, (float*)d_out);
    } else {
        // ---------- R7 fallback: direct atomics with K privatized images ----------
        const size_t IMG_BYTES = (size_t)NPIX * sizeof(float);
        const size_t AUX_BYTES = 1024 + (size_t)NM * NS * sizeof(unsigned);
        int K = 0;
        for (int k = 8; k >= 1; k >>= 1) {
            if ((size_t)k * IMG_BYTES + AUX_BYTES <= ws_size) { K = k; break; }
        }
        float* imgs;
        char*  aux;
        if (K >= 1) {
            imgs = (float*)d_ws;
            aux  = (char*)d_ws + (size_t)K * IMG_BYTES;
            hipMemsetAsync(imgs, 0, (size_t)K * IMG_BYTES, stream);
        } else {
            K    = 1;
            imgs = (float*)d_out;
            aux  = (char*)d_ws;
            hipMemsetAsync(imgs, 0, IMG_BYTES, stream);
        }
        float4*   bounds = (float4*)aux;
        unsigned* masks  = (unsigned*)(aux + 1024);

        mirror_bounds_kernel<<<NM, 256, 0, stream>>>(mpts, mpos, mrot, bounds);
        mask_kernel<<<(NM * NS + 255) / 256, 256, 0, stream>>>(
            sources, cp1, cp2, crad, bp1, bp2, bounds, masks);

        dim3 grid(NP / 256, NS / SPT, NM);
        render_kernel<<<grid, 256, 0, stream>>>(sources, mpts, mnrm, mpos, mrot,
                                                cp1, cp2, crad, bp1, bp2, spp, spn,
                                                masks, imgs, K);
        if (imgs != (float*)d_out) {
            reduce_kernel<<<NPIX / 256, 256, 0, stream>>>(imgs, K, (float*)d_out);
        }
    }
}